// Round 5
// baseline (852.843 us; speedup 1.0000x reference)
//
#include <hip/hip_runtime.h>
#include <math.h>
#include <stdio.h>

#define BB 4
#define NP 65536

typedef unsigned short u16;
typedef unsigned int u32;
typedef __attribute__((ext_vector_type(8))) short short8;
typedef __attribute__((ext_vector_type(4))) float f32x4;
typedef __attribute__((ext_vector_type(2))) float f32x2;

__device__ __forceinline__ float bf2f(u16 u) { return __uint_as_float((u32)u << 16); }
__device__ __forceinline__ u16 f2bf(float f) {
  u32 u = __float_as_uint(f);
  u = (u + 0x7FFFu + ((u >> 16) & 1u)) >> 16;
  return (u16)u;
}
__device__ __forceinline__ float gelu_f(float x) {
  return 0.5f * x * (1.f + erff(x * 0.70710678118654752f));
}
__device__ __forceinline__ float wlo(u32 w) { return __uint_as_float(w << 16); }
__device__ __forceinline__ float whi(u32 w) { return __uint_as_float(w & 0xFFFF0000u); }

// ---------------- transpose (B,N,C)->(B,C,N) fp32 + xb1 ROW layout bf16 + SCA mean partials
__global__ __launch_bounds__(256) void k_trans_stats(const float* __restrict__ x,
                                                     float* __restrict__ xi,
                                                     u16* __restrict__ xb1,
                                                     float* __restrict__ meanraw) {
  __shared__ float tile[64 * 65];
  __shared__ float s1a[64], s2a[64], sig[64], cm[64];
  int b = blockIdx.y;
  long n0 = (long)blockIdx.x * 64;
  int t = threadIdx.x;
  for (int i = t; i < 4096; i += 256) {
    int nl = i >> 6, c = i & 63;
    tile[nl * 65 + c] = x[((long)b * NP + n0 + nl) * 64 + c];
  }
  if (t < 64) { s1a[t] = 0.f; s2a[t] = 0.f; cm[t] = 0.f; }
  __syncthreads();
  {
    int nl = t & 63, part = t >> 6;
    float p1 = 0.f, p2 = 0.f;
    for (int cc = 0; cc < 16; cc++) {
      float v = tile[nl * 65 + part * 16 + cc];
      p1 += v; p2 += v * v;
    }
    atomicAdd(&s1a[nl], p1); atomicAdd(&s2a[nl], p2);
  }
  __syncthreads();
  if (t < 64) {
    float m = s1a[t] * (1.f / 64.f);
    float var = s2a[t] * (1.f / 64.f) - m * m;
    sig[t] = rsqrtf(var + 1e-5f);
  }
  __syncthreads();
  int nl = t & 63;
  int part = t >> 6;
  float sgv = sig[nl];
  for (int j = 0; j < 16; j++) {
    int i = t + 256 * j;
    int c = i >> 6;
    float v = tile[nl * 65 + c];
    xi[((long)b * 64 + c) * NP + n0 + nl] = v;
    float a = v * sgv;
    for (int off = 32; off; off >>= 1) a += __shfl_down(a, off);
    if ((t & 63) == 0) atomicAdd(&cm[c], a);
  }
  {
    u16* rp = xb1 + ((long)b * NP + n0 + nl) * 64 + part * 16;
    uint4 pk[2];
    u32 tmp[8];
#pragma unroll
    for (int g = 0; g < 2; g++) {
#pragma unroll
      for (int e = 0; e < 4; e++) {
        float v0 = tile[nl * 65 + part * 16 + g * 8 + 2 * e] * sgv;
        float v1 = tile[nl * 65 + part * 16 + g * 8 + 2 * e + 1] * sgv;
        tmp[e] = (u32)f2bf(v0) | ((u32)f2bf(v1) << 16);
      }
      pk[g].x = tmp[0]; pk[g].y = tmp[1]; pk[g].z = tmp[2]; pk[g].w = tmp[3];
      *(uint4*)(rp + g * 8) = pk[g];
    }
  }
  __syncthreads();
  if (t < 64) atomicAdd(&meanraw[b * 64 + t], cm[t]);
}

// ---------------- xsca
__global__ void k_xsca(const float* __restrict__ meanraw, const float* __restrict__ lnw,
                       const float* __restrict__ sca_w, const float* __restrict__ sca_b,
                       float* __restrict__ xsca) {
  int t = threadIdx.x;
  int b = t >> 6, co = t & 63;
  float a = sca_b[co];
  for (int ci = 0; ci < 64; ci++)
    a += sca_w[co * 64 + ci] * meanraw[b * 64 + ci] * lnw[ci] * (1.f / 65536.f);
  xsca[t] = a;
}

// ---------------- weight prep (bf16 [co][64ci], LN folded)
__global__ void k_foldW1b(const float* __restrict__ qkv_w, const float* __restrict__ dw1_w,
                          const float* __restrict__ lnw, u16* __restrict__ W1b) {
  int i = blockIdx.x * 256 + threadIdx.x;
  if (i < 320 * 64) {
    int co = i >> 6, ci = i & 63;
    float w = (co < 192) ? qkv_w[co * 64 + ci] : dw1_w[(co - 192) * 64 + ci];
    W1b[i] = f2bf(w * lnw[ci]);
  }
}
__global__ void k_foldW2b(const float* __restrict__ pin_w, const float* __restrict__ lnw,
                          u16* __restrict__ W2b) {
  int i = blockIdx.x * 256 + threadIdx.x;
  if (i < 384 * 64) {
    int co = i >> 6, ci = i & 63;
    float v = 0.f;
    if (co < 340) {
      int pair = co >> 1, which = co & 1;
      v = pin_w[(pair + which * 170) * 64 + ci] * lnw[ci];
    }
    W2b[i] = f2bf(v);
  }
}
__global__ void k_foldWpb(const float* __restrict__ w, u16* __restrict__ Wpb) {
  int i = blockIdx.x * 256 + threadIdx.x;
  if (i < 4096) Wpb[i] = f2bf(w[i]);
}
// pout weights -> bf16 [64co][192ci], zero-padded ci>=170
__global__ void k_tpoutb(const float* __restrict__ w, u16* __restrict__ Wob) {
  int i = blockIdx.x * 256 + threadIdx.x;
  if (i < 64 * 192) {
    int co = i / 192, ci = i - co * 192;
    Wob[i] = (ci < 170) ? f2bf(w[co * 170 + ci]) : (u16)0;
  }
}

// ---------------- MFMA GEMM: out[co][px] = sum_ci W[co][ci] * in[px][ci]
template <int EPI>
__global__ __launch_bounds__(256) void k_mgemm(const u16* __restrict__ in, long in_bs,
                                               const u16* __restrict__ W,
                                               u16* __restrict__ outp, long out_bs,
                                               float* __restrict__ xo,
                                               u16* __restrict__ xb2r) {
  int t = threadIdx.x;
  int lane = t & 63, wv = t >> 6;
  int l15 = lane & 15, quad = lane >> 4;
  int pxw = blockIdx.x * 256 + wv * 64;
  int co0 = blockIdx.y * 64;
  int b = blockIdx.z;
  const u16* inb = in + (long)b * in_bs;

  short8 aw[4][2];
#pragma unroll
  for (int t4 = 0; t4 < 4; t4++)
#pragma unroll
    for (int kf = 0; kf < 2; kf++)
      aw[t4][kf] = *(const short8*)(W + (long)(co0 + t4 * 16 + l15) * 64 + kf * 32 + quad * 8);

  f32x4 acc[4][4];
#pragma unroll
  for (int t4 = 0; t4 < 4; t4++)
#pragma unroll
    for (int p = 0; p < 4; p++) acc[t4][p] = (f32x4){0.f, 0.f, 0.f, 0.f};

#pragma unroll
  for (int p = 0; p < 4; p++) {
    long px = pxw + p * 16 + l15;
    short8 bf0 = *(const short8*)(inb + px * 64 + quad * 8);
    short8 bf1 = *(const short8*)(inb + px * 64 + 32 + quad * 8);
#pragma unroll
    for (int t4 = 0; t4 < 4; t4++) {
      acc[t4][p] = __builtin_amdgcn_mfma_f32_16x16x32_bf16(aw[t4][0], bf0, acc[t4][p], 0, 0, 0);
      acc[t4][p] = __builtin_amdgcn_mfma_f32_16x16x32_bf16(aw[t4][1], bf1, acc[t4][p], 0, 0, 0);
    }
  }

  if (EPI == 0) {
    u16* ob = outp + (long)b * out_bs;
#pragma unroll
    for (int t4 = 0; t4 < 4; t4++)
#pragma unroll
      for (int p = 0; p < 4; p++) {
#pragma unroll
        for (int reg = 0; reg < 4; reg++) {
          int co = co0 + t4 * 16 + quad * 4 + reg;
          ob[(long)co * NP + pxw + p * 16 + l15] = f2bf(acc[t4][p][reg]);
        }
      }
  } else {
#pragma unroll
    for (int p = 0; p < 4; p++) {
      long px = pxw + p * 16 + l15;
      float xv[16];
      float s1 = 0.f, s2 = 0.f;
#pragma unroll
      for (int t4 = 0; t4 < 4; t4++)
#pragma unroll
        for (int reg = 0; reg < 4; reg++) {
          int co = t4 * 16 + quad * 4 + reg;
          float v = xo[((long)b * 64 + co) * NP + px] + acc[t4][p][reg];
          xv[t4 * 4 + reg] = v;
          s1 += v; s2 += v * v;
        }
      s1 += __shfl_xor(s1, 16); s2 += __shfl_xor(s2, 16);
      s1 += __shfl_xor(s1, 32); s2 += __shfl_xor(s2, 32);
      float m = s1 * (1.f / 64.f);
      float var = s2 * (1.f / 64.f) - m * m;
      float sg = rsqrtf(var + 1e-5f);
#pragma unroll
      for (int t4 = 0; t4 < 4; t4++)
#pragma unroll
        for (int reg = 0; reg < 4; reg++) {
          int co = t4 * 16 + quad * 4 + reg;
          xo[((long)b * 64 + co) * NP + px] = xv[t4 * 4 + reg];
        }
      u16* rp = xb2r + ((long)b * NP + px) * 64;
#pragma unroll
      for (int t4 = 0; t4 < 4; t4++) {
        u32 u0 = (u32)f2bf(xv[t4 * 4 + 0] * sg) | ((u32)f2bf(xv[t4 * 4 + 1] * sg) << 16);
        u32 u1 = (u32)f2bf(xv[t4 * 4 + 2] * sg) | ((u32)f2bf(xv[t4 * 4 + 3] * sg) << 16);
        uint2 pk; pk.x = u0; pk.y = u1;
        *(uint2*)(rp + t4 * 16 + quad * 4) = pk;
      }
    }
  }
}

// ---------------- strip-2 dw3x3: 2 output rows (y0,y0+1) x 4 px/lane, packed f32x2 FMA.
// Loads the 4 needed rows once each; halo via 2 shfls/row; lane 0/63 = image boundary.
__device__ __forceinline__ void dw4x2(const u16* __restrict__ img, int y0, int x0, int lane,
                                      const float* __restrict__ w9,
                                      f32x2 o0[2], f32x2 o1[2]) {
  o0[0] = (f32x2){0.f, 0.f}; o0[1] = (f32x2){0.f, 0.f};
  o1[0] = (f32x2){0.f, 0.f}; o1[1] = (f32x2){0.f, 0.f};
#pragma unroll
  for (int r = -1; r <= 2; r++) {
    int row = y0 + r;
    uint2 q; q.x = 0u; q.y = 0u;
    if ((unsigned)row < 256u) q = *(const uint2*)(img + row * 256 + x0);
    u32 qly = (u32)__shfl_up((int)q.y, 1);
    u32 qrx = (u32)__shfl_down((int)q.x, 1);
    if (lane == 0)  qly = 0u;
    if (lane == 63) qrx = 0u;
    float f[6];
    f[0] = whi(qly); f[1] = wlo(q.x); f[2] = whi(q.x);
    f[3] = wlo(q.y); f[4] = whi(q.y); f[5] = wlo(qrx);
    f32x2 fp[5];
#pragma unroll
    for (int i = 0; i < 5; i++) fp[i] = (f32x2){f[i], f[i + 1]};
    if (r <= 1) {
      const float* wr = w9 + (r + 1) * 3;
#pragma unroll
      for (int dx = 0; dx < 3; dx++) {
        f32x2 w2 = {wr[dx], wr[dx]};
        o0[0] += w2 * fp[dx]; o0[1] += w2 * fp[dx + 2];
      }
    }
    if (r >= 0) {
      const float* wr = w9 + r * 3;
#pragma unroll
      for (int dx = 0; dx < 3; dx++) {
        f32x2 w2 = {wr[dx], wr[dx]};
        o1[0] += w2 * fp[dx]; o1[1] += w2 * fp[dx + 2];
      }
    }
  }
}

// ---------------- q/k/v depthwise + per-pixel norm (q,k only), strip-2.
__global__ __launch_bounds__(256) void k_dwqkv(const u16* __restrict__ P,
                                               const float* __restrict__ dww,
                                               u16* __restrict__ Qn, u16* __restrict__ Kn,
                                               u16* __restrict__ Vn) {
  int t = threadIdx.x;
  int lane = t & 63, wv = t >> 6;
  int by = blockIdx.y;
  int ph = by >> 3, h = by & 7;
  int b = blockIdx.z;
  int y0 = (blockIdx.x * 4 + wv) * 2;
  int x0 = lane * 4;
  int cbase = ph * 64 + h * 8;
  const u16* Pb = P + ((long)b * 192 + cbase) * NP;
  const float* wb = dww + cbase * 9;

  f32x2 v[8][2][2];
#pragma unroll
  for (int c = 0; c < 8; c++)
    dw4x2(Pb + (long)c * NP, y0, x0, lane, wb + c * 9, v[c][0], v[c][1]);

  if (ph < 2) {   // q and k are L2-normalized over the 8 channels per pixel
#pragma unroll
    for (int row = 0; row < 2; row++) {
      f32x2 s2a = {0.f, 0.f}, s2b = {0.f, 0.f};
#pragma unroll
      for (int c = 0; c < 8; c++) {
        s2a += v[c][row][0] * v[c][row][0];
        s2b += v[c][row][1] * v[c][row][1];
      }
      f32x2 ia, ib;
      ia.x = 1.f / (sqrtf(s2a.x) + 1e-6f); ia.y = 1.f / (sqrtf(s2a.y) + 1e-6f);
      ib.x = 1.f / (sqrtf(s2b.x) + 1e-6f); ib.y = 1.f / (sqrtf(s2b.y) + 1e-6f);
#pragma unroll
      for (int c = 0; c < 8; c++) { v[c][row][0] *= ia; v[c][row][1] *= ib; }
    }
  }
  u16* dst = (ph == 0) ? Qn : (ph == 1) ? Kn : Vn;
#pragma unroll
  for (int c = 0; c < 8; c++)
#pragma unroll
    for (int row = 0; row < 2; row++) {
      ushort4 st;
      st.x = f2bf(v[c][row][0].x); st.y = f2bf(v[c][row][0].y);
      st.z = f2bf(v[c][row][1].x); st.w = f2bf(v[c][row][1].y);
      *(ushort4*)(dst + ((long)b * 64 + h * 8 + c) * NP + (long)(y0 + row) * 256 + x0) = st;
    }
}

// ---------------- stats: kv[8][8], ksum[8], vsum[8] per (b,h) from planar Kn/Vn.
__global__ __launch_bounds__(256) void k_stats(const u16* __restrict__ Kn,
                                               const u16* __restrict__ Vn,
                                               float* __restrict__ stats) {
  int t = threadIdx.x;
  int lane = t & 63;
  int h = blockIdx.y, b = blockIdx.z;
  long px = (long)blockIdx.x * 1024 + t * 4;
  const u16* Kb = Kn + ((long)b * 64 + h * 8) * NP + px;
  const u16* Vb = Vn + ((long)b * 64 + h * 8) * NP + px;
  float kf[8][4], vf[8][4];
#pragma unroll
  for (int c = 0; c < 8; c++) {
    ushort4 ku = *(const ushort4*)(Kb + (long)c * NP);
    kf[c][0] = bf2f(ku.x); kf[c][1] = bf2f(ku.y);
    kf[c][2] = bf2f(ku.z); kf[c][3] = bf2f(ku.w);
  }
#pragma unroll
  for (int c = 0; c < 8; c++) {
    ushort4 vu = *(const ushort4*)(Vb + (long)c * NP);
    vf[c][0] = bf2f(vu.x); vf[c][1] = bf2f(vu.y);
    vf[c][2] = bf2f(vu.z); vf[c][3] = bf2f(vu.w);
  }
  __shared__ float sred[80];
  if (t < 80) sred[t] = 0.f;
  __syncthreads();
#pragma unroll
  for (int i = 0; i < 8; i++) {
#pragma unroll
    for (int j = 0; j < 8; j++) {
      float a = kf[i][0] * vf[j][0] + kf[i][1] * vf[j][1] +
                kf[i][2] * vf[j][2] + kf[i][3] * vf[j][3];
      a += __shfl_xor(a, 1); a += __shfl_xor(a, 2); a += __shfl_xor(a, 4);
      a += __shfl_xor(a, 8); a += __shfl_xor(a, 16); a += __shfl_xor(a, 32);
      if (lane == ((i * 8 + j) & 63)) atomicAdd(&sred[i * 8 + j], a);
    }
    {
      float a = kf[i][0] + kf[i][1] + kf[i][2] + kf[i][3];
      a += __shfl_xor(a, 1); a += __shfl_xor(a, 2); a += __shfl_xor(a, 4);
      a += __shfl_xor(a, 8); a += __shfl_xor(a, 16); a += __shfl_xor(a, 32);
      if (lane == ((64 + i) & 63)) atomicAdd(&sred[64 + i], a);
    }
    {
      float a = vf[i][0] + vf[i][1] + vf[i][2] + vf[i][3];
      a += __shfl_xor(a, 1); a += __shfl_xor(a, 2); a += __shfl_xor(a, 4);
      a += __shfl_xor(a, 8); a += __shfl_xor(a, 16); a += __shfl_xor(a, 32);
      if (lane == ((72 + i) & 63)) atomicAdd(&sred[72 + i], a);
    }
  }
  __syncthreads();
  if (t < 80) atomicAdd(&stats[((long)b * 8 + h) * 80 + t], sred[t]);
}

// ---------------- dw1-pairs -> grouped dw2 3x3 -> gelu (strip-2)
__global__ __launch_bounds__(256) void k_dwg(const u16* __restrict__ P,
                                             const float* __restrict__ dw2_w,
                                             u16* __restrict__ G) {
  int t = threadIdx.x;
  int lane = t & 63, wv = t >> 6;
  int c = blockIdx.y, b = blockIdx.z;
  int y0 = (blockIdx.x * 4 + wv) * 2;
  int x0 = lane * 4;
  const u16* Pb = P + (long)b * 128 * NP;
  f32x2 d1r0[2], d1r1[2], d2r0[2], d2r1[2];
  dw4x2(Pb + (long)(2 * c) * NP, y0, x0, lane, dw2_w + c * 18, d1r0, d1r1);
  dw4x2(Pb + (long)(2 * c + 1) * NP, y0, x0, lane, dw2_w + c * 18 + 9, d2r0, d2r1);
  u16* gp = G + ((long)b * 64 + c) * NP + (long)y0 * 256 + x0;
  ushort4 s0, s1;
  s0.x = f2bf(gelu_f(d1r0[0].x + d2r0[0].x)); s0.y = f2bf(gelu_f(d1r0[0].y + d2r0[0].y));
  s0.z = f2bf(gelu_f(d1r0[1].x + d2r0[1].x)); s0.w = f2bf(gelu_f(d1r0[1].y + d2r0[1].y));
  s1.x = f2bf(gelu_f(d1r1[0].x + d2r1[0].x)); s1.y = f2bf(gelu_f(d1r1[0].y + d2r1[0].y));
  s1.z = f2bf(gelu_f(d1r1[1].x + d2r1[1].x)); s1.w = f2bf(gelu_f(d1r1[1].y + d2r1[1].y));
  *(ushort4*)(gp) = s0;
  *(ushort4*)(gp + 256) = s1;
}

// ---------------- FFN dw pair + gelu gate (pair-interleaved P, strip-2)
__global__ __launch_bounds__(256) void k_dwgate(const u16* __restrict__ P,
                                                const float* __restrict__ dww,
                                                u16* __restrict__ Hb) {
  int t = threadIdx.x;
  int lane = t & 63, wv = t >> 6;
  int c = blockIdx.y, b = blockIdx.z;
  int y0 = (blockIdx.x * 4 + wv) * 2;
  int x0 = lane * 4;
  const u16* Pb = P + (long)b * 384 * NP;
  f32x2 d1r0[2], d1r1[2], d2r0[2], d2r1[2];
  dw4x2(Pb + (long)(2 * c) * NP, y0, x0, lane, dww + c * 9, d1r0, d1r1);
  dw4x2(Pb + (long)(2 * c + 1) * NP, y0, x0, lane, dww + (170 + c) * 9, d2r0, d2r1);
  u16* hp = Hb + ((long)b * 170 + c) * NP + (long)y0 * 256 + x0;
  ushort4 s0, s1;
  s0.x = f2bf(gelu_f(d1r0[0].x) * d2r0[0].x); s0.y = f2bf(gelu_f(d1r0[0].y) * d2r0[0].y);
  s0.z = f2bf(gelu_f(d1r0[1].x) * d2r0[1].x); s0.w = f2bf(gelu_f(d1r0[1].y) * d2r0[1].y);
  s1.x = f2bf(gelu_f(d1r1[0].x) * d2r1[0].x); s1.y = f2bf(gelu_f(d1r1[0].y) * d2r1[0].y);
  s1.z = f2bf(gelu_f(d1r1[1].x) * d2r1[1].x); s1.w = f2bf(gelu_f(d1r1[1].y) * d2r1[1].y);
  *(ushort4*)(hp) = s0;
  *(ushort4*)(hp + 256) = s1;
}

// ---------------- refine conv (3/5/7), single-phase strip-2, raw partial sums.
// One wave = one (head, phase q|k) x 2 output rows x full 256-px row.
template <int WIN>
__device__ void refine1(const u16* __restrict__ src, const float* __restrict__ wp,
                        float bias, float* __restrict__ ro, int y0, int x0, int lane) {
  const int R = WIN / 2;
  f32x2 a0a = {bias, bias}, a0b = {bias, bias};
  f32x2 a1a = {bias, bias}, a1b = {bias, bias};
#pragma unroll 1
  for (int ch = 0; ch < 8; ch++) {
    const u16* img = src + (long)ch * NP;
    const float* wc = wp + ch * WIN * WIN;
#pragma unroll
    for (int r = -R; r <= 1 + R; r++) {
      int row = y0 + r;
      uint2 q; q.x = 0u; q.y = 0u;
      if ((unsigned)row < 256u) q = *(const uint2*)(img + row * 256 + x0);
      float f[4 + 2 * R];
      f[R + 0] = wlo(q.x); f[R + 1] = whi(q.x);
      f[R + 2] = wlo(q.y); f[R + 3] = whi(q.y);
      {
        u32 qly = (u32)__shfl_up((int)q.y, 1);
        u32 qrx = (u32)__shfl_down((int)q.x, 1);
        if (lane == 0)  qly = 0u;
        if (lane == 63) qrx = 0u;
        f[R - 1] = whi(qly); f[R + 4] = wlo(qrx);
        if (R >= 2) { f[R - 2] = wlo(qly); f[R + 5] = whi(qrx); }
        if (R >= 3) {
          u32 qlx = (u32)__shfl_up((int)q.x, 1);
          u32 qry = (u32)__shfl_down((int)q.y, 1);
          if (lane == 0)  qlx = 0u;
          if (lane == 63) qry = 0u;
          f[0] = whi(qlx); f[R + 6] = wlo(qry);
        }
      }
      f32x2 fp[3 + 2 * R];
#pragma unroll
      for (int i = 0; i < 3 + 2 * R; i++) fp[i] = (f32x2){f[i], f[i + 1]};
      if (r <= R) {               // contributes to output row y0 (dy = r)
        const float* w0 = wc + (r + R) * WIN;
#pragma unroll
        for (int dx = 0; dx < WIN; dx++) {
          f32x2 w2 = {w0[dx], w0[dx]};
          a0a += w2 * fp[dx];
          a0b += w2 * fp[dx + 2];
        }
      }
      if (r >= 1 - R) {           // contributes to output row y0+1 (dy = r-1)
        const float* w1 = wc + (r - 1 + R) * WIN;
#pragma unroll
        for (int dx = 0; dx < WIN; dx++) {
          f32x2 w2 = {w1[dx], w1[dx]};
          a1a += w2 * fp[dx];
          a1b += w2 * fp[dx + 2];
        }
      }
    }
  }
  float4 o0, o1;
  o0.x = a0a.x; o0.y = a0a.y; o0.z = a0b.x; o0.w = a0b.y;
  o1.x = a1a.x; o1.y = a1a.y; o1.z = a1b.x; o1.w = a1b.y;
  *(float4*)(ro + (long)y0 * 256 + x0) = o0;
  *(float4*)(ro + (long)(y0 + 1) * 256 + x0) = o1;
}

__global__ __launch_bounds__(256) void k_refine(
    const u16* __restrict__ Qn, const u16* __restrict__ Kn,
    const float* __restrict__ r3w, const float* __restrict__ r3b,
    const float* __restrict__ r5w, const float* __restrict__ r5b,
    const float* __restrict__ r7w, const float* __restrict__ r7b,
    float* __restrict__ refQ, float* __restrict__ refK) {
  int t = threadIdx.x, lane = t & 63, wv = t >> 6;
  int yy = blockIdx.y;                  // 16 = (head, phase); heavy WIN=7 heads first
  int h = ((yy >> 1) + 5) & 7;
  int ph = yy & 1;
  int b = blockIdx.z;
  int y0 = (blockIdx.x * 4 + wv) * 2;   // block = 8 contiguous rows (L2 halo reuse)
  int x0 = lane * 4;
  const u16* src = (ph ? Kn : Qn) + ((long)b * 64 + h * 8) * NP;
  float* ro = (ph ? refK : refQ) + ((long)(b * 8 + h)) * NP;
  if (h < 2) {
    float bias = ph ? 0.f : r3b[h];
    refine1<3>(src, r3w + h * 16 * 9 + ph * 8 * 9, bias, ro, y0, x0, lane);
  } else if (h < 5) {
    float bias = ph ? 0.f : r5b[h - 2];
    refine1<5>(src, r5w + (h - 2) * 16 * 25 + ph * 8 * 25, bias, ro, y0, x0, lane);
  } else {
    float bias = ph ? 0.f : r7b[h - 5];
    refine1<7>(src, r7w + (h - 5) * 16 * 49 + ph * 8 * 49, bias, ro, y0, x0, lane);
  }
}

// ---------------- attention epilogue -> O row layout [px][64]; sigmoid(refQ+refK) here
__global__ __launch_bounds__(256) void k_attn(
    const u16* __restrict__ Qn, const float* __restrict__ stats,
    const float* __restrict__ refQ, const float* __restrict__ refK,
    const float* __restrict__ temp,
    const float* __restrict__ xsca, const u16* __restrict__ G,
    u16* __restrict__ Orows) {
  int b = blockIdx.y;
  int t = threadIdx.x;
  __shared__ float s[640];
  __shared__ float sx[64];
  for (int i = t; i < 640; i += 256) s[i] = stats[(long)b * 640 + i];
  if (t < 64) sx[t] = xsca[b * 64 + t];
  __syncthreads();
  long n = (long)blockIdx.x * 256 + t;
  u16* rp = Orows + ((long)b * NP + n) * 64;
#pragma unroll
  for (int h = 0; h < 8; h++) {
    const float* sh = s + h * 80;
    float q[8];
#pragma unroll
    for (int i = 0; i < 8; i++) q[i] = bf2f(Qn[((long)b * 64 + h * 8 + i) * NP + n]);
    float den = 65536.f + 1e-6f;
#pragma unroll
    for (int i = 0; i < 8; i++) den += q[i] * sh[64 + i];
    float rsum = refQ[((long)(b * 8 + h)) * NP + n] + refK[((long)(b * 8 + h)) * NP + n];
    float tr = temp[h] / ((1.f + expf(-rsum)) * den);
    u32 pk[4];
#pragma unroll
    for (int j2 = 0; j2 < 4; j2++) {
      float o01[2];
#pragma unroll
      for (int e = 0; e < 2; e++) {
        int j = j2 * 2 + e;
        float num = sh[72 + j];
#pragma unroll
        for (int i = 0; i < 8; i++) num += q[i] * sh[i * 8 + j];
        int ci = h * 8 + j;
        o01[e] = num * tr * sx[ci] * bf2f(G[((long)b * 64 + ci) * NP + n]);
      }
      pk[j2] = (u32)f2bf(o01[0]) | ((u32)f2bf(o01[1]) << 16);
    }
    uint4 v; v.x = pk[0]; v.y = pk[1]; v.z = pk[2]; v.w = pk[3];
    *(uint4*)(rp + h * 8) = v;
  }
}

// ---------------- pout MFMA GEMM (192-padded -> 64co) + fp32 residual
__global__ __launch_bounds__(256) void k_pout(const u16* __restrict__ Hb,
                                              const u16* __restrict__ Wob,
                                              float* __restrict__ xo) {
  __shared__ u16 tile[64 * 196];   // 25088 B
  int t = threadIdx.x;
  int lane = t & 63, wv = t >> 6;
  int l15 = lane & 15, quad = lane >> 4;
  int b = blockIdx.z;
  int px0 = blockIdx.x * 64;
  const u16* ib = Hb + (long)b * 170 * NP + px0;
#pragma unroll
  for (int i = 0; i < 12; i++) {
    int task = t + i * 256;
    int q = task >> 6, px = task & 63;
    int ci0 = q * 4;
    u32 w0 = 0u, w1 = 0u;
    if (ci0 < 170)     w0 = (u32)ib[(long)ci0 * NP + px];
    if (ci0 + 1 < 170) w0 |= ((u32)ib[(long)(ci0 + 1) * NP + px]) << 16;
    if (ci0 + 2 < 170) w1 = (u32)ib[(long)(ci0 + 2) * NP + px];
    if (ci0 + 3 < 170) w1 |= ((u32)ib[(long)(ci0 + 3) * NP + px]) << 16;
    uint2 pk; pk.x = w0; pk.y = w1;
    *(uint2*)(tile + px * 196 + ci0) = pk;
  }
  __syncthreads();

  f32x4 acc[4];
#pragma unroll
  for (int t4 = 0; t4 < 4; t4++) acc[t4] = (f32x4){0.f, 0.f, 0.f, 0.f};
  const u16* tb = tile + (wv * 16 + l15) * 196;
#pragma unroll
  for (int kf = 0; kf < 6; kf++) {
    union { uint2 u2[2]; short8 s8; } cv;
    cv.u2[0] = *(const uint2*)(tb + kf * 32 + quad * 8);
    cv.u2[1] = *(const uint2*)(tb + kf * 32 + quad * 8 + 4);
    short8 bfr = cv.s8;
#pragma unroll
    for (int t4 = 0; t4 < 4; t4++) {
      short8 aw = *(const short8*)(Wob + (long)(t4 * 16 + l15) * 192 + kf * 32 + quad * 8);
      acc[t4] = __builtin_amdgcn_mfma_f32_16x16x32_bf16(aw, bfr, acc[t4], 0, 0, 0);
    }
  }
  long pxg = px0 + wv * 16 + l15;
  float* xb = xo + (long)b * 64 * NP;
#pragma unroll
  for (int t4 = 0; t4 < 4; t4++)
#pragma unroll
    for (int reg = 0; reg < 4; reg++) {
      int co = t4 * 16 + quad * 4 + reg;
      xb[(long)co * NP + pxg] += acc[t4][reg];
    }
}

// ================================================================ launcher
extern "C" void kernel_launch(void* const* d_in, const int* in_sizes, int n_in,
                              void* d_out, int out_size, void* d_ws, size_t ws_size,
                              hipStream_t stream) {
  const float* x        = (const float*)d_in[0];
  const float* ln1_w    = (const float*)d_in[1];
  const float* sca_w    = (const float*)d_in[2];
  const float* sca_b    = (const float*)d_in[3];
  const float* dw1_w    = (const float*)d_in[4];
  const float* dw2_w    = (const float*)d_in[5];
  const float* qkv_w    = (const float*)d_in[6];
  const float* qkv_dw_w = (const float*)d_in[7];
  const float* temp     = (const float*)d_in[8];
  const float* r3w = (const float*)d_in[9],  *r3b = (const float*)d_in[10];
  const float* r5w = (const float*)d_in[11], *r5b = (const float*)d_in[12];
  const float* r7w = (const float*)d_in[13], *r7b = (const float*)d_in[14];
  const float* proj_w   = (const float*)d_in[15];
  const float* ln2_w    = (const float*)d_in[16];
  const float* pin_w    = (const float*)d_in[17];
  const float* ffn_dw_w = (const float*)d_in[18];
  const float* pout_w   = (const float*)d_in[19];
  float* out = (float*)d_out;
  char* wsb = (char*)d_ws;

  const size_t Mi = 1048576;
  u16* xb1   = (u16*)(wsb);                  // rows [B][NP][64]  (later xb2)
  u16* Qn    = (u16*)(wsb + 32 * Mi);        // planar
  u16* Kn    = (u16*)(wsb + 64 * Mi);        // planar (later O rows)
  u16* G     = (u16*)(wsb + 96 * Mi);        // planar; holds Vn transiently before k_dwg
  u16* Preg  = (u16*)(wsb + 128 * Mi);       // 96 MiB planar
  float* refQ    = (float*)(wsb + 224 * Mi); // 8 MiB (refine q-partial)
  float* refK    = (float*)(wsb + 128 * Mi); // 8 MiB, reuses Preg (free between dwg and FFN)
  float* Fm      = (float*)(wsb + 232 * Mi);
  float* stats   = Fm;
  float* meanraw = Fm + 2560;
  float* xscab   = Fm + 2816;
  u16* Wob       = (u16*)(Fm + 3072);        // 64x192 bf16 pout weights
  u16* W1b = (u16*)(Fm + 13952);
  u16* W2b = W1b + 20480;
  u16* Wpb = W2b + 24576;
  u16* xb2 = xb1;
  u16* Orows = Kn;
  u16* Hb = Qn;
  u16* Vn = G;   // V planes live only between k_dwqkv and k_stats; G written later by k_dwg

  const size_t needed = 232 * Mi + 13952 * 4 + (20480 + 24576 + 4096) * 2;
  if (ws_size < needed) {
    fprintf(stderr, "kernel_launch: ws_size %zu < needed %zu\n", ws_size, needed);
    return;
  }

  hipMemsetAsync(stats, 0, (2560 + 256) * 4, stream);
  k_foldW1b<<<80, 256, 0, stream>>>(qkv_w, dw1_w, ln1_w, W1b);
  k_foldW2b<<<96, 256, 0, stream>>>(pin_w, ln2_w, W2b);
  k_foldWpb<<<16, 256, 0, stream>>>(proj_w, Wpb);
  k_tpoutb<<<48, 256, 0, stream>>>(pout_w, Wob);

  k_trans_stats<<<dim3(1024, BB), 256, 0, stream>>>(x, out, xb1, meanraw);
  k_xsca<<<1, 256, 0, stream>>>(meanraw, ln1_w, sca_w, sca_b, xscab);

  k_mgemm<0><<<dim3(256, 3, BB), 256, 0, stream>>>(xb1, (long)NP * 64, W1b,
                                                   Preg, 192L * NP, nullptr, nullptr);
  k_dwqkv<<<dim3(32, 24, BB), 256, 0, stream>>>(Preg, qkv_dw_w, Qn, Kn, Vn);
  k_stats<<<dim3(64, 8, BB), 256, 0, stream>>>(Kn, Vn, stats);

  k_mgemm<0><<<dim3(256, 2, BB), 256, 0, stream>>>(xb1, (long)NP * 64, W1b + 192 * 64,
                                                   Preg, 128L * NP, nullptr, nullptr);
  k_dwg<<<dim3(32, 64, BB), 256, 0, stream>>>(Preg, dw2_w, G);

  k_refine<<<dim3(32, 16, BB), 256, 0, stream>>>(Qn, Kn, r3w, r3b, r5w, r5b, r7w, r7b,
                                                 refQ, refK);
  k_attn<<<dim3(256, BB), 256, 0, stream>>>(Qn, stats, refQ, refK, temp, xscab, G, Orows);

  k_mgemm<1><<<dim3(256, 1, BB), 256, 0, stream>>>(Orows, (long)NP * 64, Wpb,
                                                   nullptr, 0, out, xb2);

  for (int pass = 0; pass < 2; pass++) {
    k_mgemm<0><<<dim3(256, 6, 2), 256, 0, stream>>>(xb2 + (long)pass * 2 * NP * 64,
                                                    (long)NP * 64, W2b,
                                                    Preg, 384L * NP, nullptr, nullptr);
    k_dwgate<<<dim3(32, 170, 2), 256, 0, stream>>>(Preg, ffn_dw_w,
                                                   Hb + (long)pass * 2 * 170 * NP);
  }
  k_pout<<<dim3(1024, 1, BB), 256, 0, stream>>>(Hb, Wob, out);
}

// Round 6
// 723.334 us; speedup vs baseline: 1.1790x; 1.1790x over previous
//
#include <hip/hip_runtime.h>
#include <math.h>
#include <stdio.h>

#define BB 4
#define NP 65536

typedef unsigned short u16;
typedef unsigned int u32;
typedef __attribute__((ext_vector_type(8))) short short8;
typedef __attribute__((ext_vector_type(4))) float f32x4;
typedef __attribute__((ext_vector_type(2))) float f32x2;

__device__ __forceinline__ float bf2f(u16 u) { return __uint_as_float((u32)u << 16); }
__device__ __forceinline__ u16 f2bf(float f) {
  u32 u = __float_as_uint(f);
  u = (u + 0x7FFFu + ((u >> 16) & 1u)) >> 16;
  return (u16)u;
}
__device__ __forceinline__ float gelu_f(float x) {
  return 0.5f * x * (1.f + erff(x * 0.70710678118654752f));
}
__device__ __forceinline__ float wlo(u32 w) { return __uint_as_float(w << 16); }
__device__ __forceinline__ float whi(u32 w) { return __uint_as_float(w & 0xFFFF0000u); }

// ---------------- LN1 row pass: per-pixel biasfree-LN -> xb1 bf16 rows + SCA mean partials.
// 16 lanes = one pixel (64 ch as 4x float4).  No transpose, no fp32 planar write.
__global__ __launch_bounds__(256) void k_ln1(const float* __restrict__ x,
                                             u16* __restrict__ xb1,
                                             float* __restrict__ meanraw) {
  int t = threadIdx.x;
  int b = blockIdx.y;
  int lane = t & 63;
  int cg = t & 15;
  float a0 = 0.f, a1 = 0.f, a2 = 0.f, a3 = 0.f;
#pragma unroll
  for (int it = 0; it < 8; it++) {
    long px = (long)blockIdx.x * 128 + (t >> 4) + it * 16;
    const float* xr = x + ((long)b * NP + px) * 64 + cg * 4;
    float4 v = *(const float4*)(xr);
    float s1 = v.x + v.y + v.z + v.w;
    float s2 = v.x * v.x + v.y * v.y + v.z * v.z + v.w * v.w;
    s1 += __shfl_xor(s1, 1); s2 += __shfl_xor(s2, 1);
    s1 += __shfl_xor(s1, 2); s2 += __shfl_xor(s2, 2);
    s1 += __shfl_xor(s1, 4); s2 += __shfl_xor(s2, 4);
    s1 += __shfl_xor(s1, 8); s2 += __shfl_xor(s2, 8);
    float m = s1 * (1.f / 64.f);
    float var = s2 * (1.f / 64.f) - m * m;
    float sg = rsqrtf(var + 1e-5f);
    float h0 = v.x * sg, h1 = v.y * sg, h2 = v.z * sg, h3 = v.w * sg;
    uint2 pk;
    pk.x = (u32)f2bf(h0) | ((u32)f2bf(h1) << 16);
    pk.y = (u32)f2bf(h2) | ((u32)f2bf(h3) << 16);
    *(uint2*)(xb1 + ((long)b * NP + px) * 64 + cg * 4) = pk;
    a0 += h0; a1 += h1; a2 += h2; a3 += h3;
  }
  a0 += __shfl_xor(a0, 16); a1 += __shfl_xor(a1, 16);
  a2 += __shfl_xor(a2, 16); a3 += __shfl_xor(a3, 16);
  a0 += __shfl_xor(a0, 32); a1 += __shfl_xor(a1, 32);
  a2 += __shfl_xor(a2, 32); a3 += __shfl_xor(a3, 32);
  __shared__ float cm[64];
  if (t < 64) cm[t] = 0.f;
  __syncthreads();
  if (lane < 16) {
    atomicAdd(&cm[cg * 4 + 0], a0);
    atomicAdd(&cm[cg * 4 + 1], a1);
    atomicAdd(&cm[cg * 4 + 2], a2);
    atomicAdd(&cm[cg * 4 + 3], a3);
  }
  __syncthreads();
  if (t < 64) atomicAdd(&meanraw[b * 64 + t], cm[t]);
}

// ---------------- xsca
__global__ void k_xsca(const float* __restrict__ meanraw, const float* __restrict__ lnw,
                       const float* __restrict__ sca_w, const float* __restrict__ sca_b,
                       float* __restrict__ xsca) {
  int t = threadIdx.x;
  int b = t >> 6, co = t & 63;
  float a = sca_b[co];
  for (int ci = 0; ci < 64; ci++)
    a += sca_w[co * 64 + ci] * meanraw[b * 64 + ci] * lnw[ci] * (1.f / 65536.f);
  xsca[t] = a;
}

// ---------------- weight prep (bf16 [co][64ci], LN folded)
__global__ void k_foldW1b(const float* __restrict__ qkv_w, const float* __restrict__ dw1_w,
                          const float* __restrict__ lnw, u16* __restrict__ W1b) {
  int i = blockIdx.x * 256 + threadIdx.x;
  if (i < 320 * 64) {
    int co = i >> 6, ci = i & 63;
    float w = (co < 192) ? qkv_w[co * 64 + ci] : dw1_w[(co - 192) * 64 + ci];
    W1b[i] = f2bf(w * lnw[ci]);
  }
}
__global__ void k_foldW2b(const float* __restrict__ pin_w, const float* __restrict__ lnw,
                          u16* __restrict__ W2b) {
  int i = blockIdx.x * 256 + threadIdx.x;
  if (i < 384 * 64) {
    int co = i >> 6, ci = i & 63;
    float v = 0.f;
    if (co < 340) {
      int pair = co >> 1, which = co & 1;
      v = pin_w[(pair + which * 170) * 64 + ci] * lnw[ci];
    }
    W2b[i] = f2bf(v);
  }
}
__global__ void k_foldWpb(const float* __restrict__ w, u16* __restrict__ Wpb) {
  int i = blockIdx.x * 256 + threadIdx.x;
  if (i < 4096) Wpb[i] = f2bf(w[i]);
}
// pout weights -> bf16 [64co][192ci], zero-padded ci>=170
__global__ void k_tpoutb(const float* __restrict__ w, u16* __restrict__ Wob) {
  int i = blockIdx.x * 256 + threadIdx.x;
  if (i < 64 * 192) {
    int co = i / 192, ci = i - co * 192;
    Wob[i] = (ci < 170) ? f2bf(w[co * 170 + ci]) : (u16)0;
  }
}

// ---------------- MFMA GEMM: out[co][px] = sum_ci W[co][ci] * in[px][ci]
// EPI==1: residual read from x ROWS (fp32 (B,N,C)), write planar xo + bf16 LN2 rows.
template <int EPI>
__global__ __launch_bounds__(256) void k_mgemm(const u16* __restrict__ in, long in_bs,
                                               const u16* __restrict__ W,
                                               u16* __restrict__ outp, long out_bs,
                                               const float* __restrict__ xres,
                                               float* __restrict__ xo,
                                               u16* __restrict__ xb2r) {
  int t = threadIdx.x;
  int lane = t & 63, wv = t >> 6;
  int l15 = lane & 15, quad = lane >> 4;
  int pxw = blockIdx.x * 256 + wv * 64;
  int co0 = blockIdx.y * 64;
  int b = blockIdx.z;
  const u16* inb = in + (long)b * in_bs;

  short8 aw[4][2];
#pragma unroll
  for (int t4 = 0; t4 < 4; t4++)
#pragma unroll
    for (int kf = 0; kf < 2; kf++)
      aw[t4][kf] = *(const short8*)(W + (long)(co0 + t4 * 16 + l15) * 64 + kf * 32 + quad * 8);

  f32x4 acc[4][4];
#pragma unroll
  for (int t4 = 0; t4 < 4; t4++)
#pragma unroll
    for (int p = 0; p < 4; p++) acc[t4][p] = (f32x4){0.f, 0.f, 0.f, 0.f};

#pragma unroll
  for (int p = 0; p < 4; p++) {
    long px = pxw + p * 16 + l15;
    short8 bf0 = *(const short8*)(inb + px * 64 + quad * 8);
    short8 bf1 = *(const short8*)(inb + px * 64 + 32 + quad * 8);
#pragma unroll
    for (int t4 = 0; t4 < 4; t4++) {
      acc[t4][p] = __builtin_amdgcn_mfma_f32_16x16x32_bf16(aw[t4][0], bf0, acc[t4][p], 0, 0, 0);
      acc[t4][p] = __builtin_amdgcn_mfma_f32_16x16x32_bf16(aw[t4][1], bf1, acc[t4][p], 0, 0, 0);
    }
  }

  if (EPI == 0) {
    u16* ob = outp + (long)b * out_bs;
#pragma unroll
    for (int t4 = 0; t4 < 4; t4++)
#pragma unroll
      for (int p = 0; p < 4; p++) {
#pragma unroll
        for (int reg = 0; reg < 4; reg++) {
          int co = co0 + t4 * 16 + quad * 4 + reg;
          ob[(long)co * NP + pxw + p * 16 + l15] = f2bf(acc[t4][p][reg]);
        }
      }
  } else {
#pragma unroll
    for (int p = 0; p < 4; p++) {
      long px = pxw + p * 16 + l15;
      const float* xrow = xres + ((long)b * NP + px) * 64;
      f32x4 xr[4];
#pragma unroll
      for (int t4 = 0; t4 < 4; t4++)
        xr[t4] = *(const f32x4*)(xrow + t4 * 16 + quad * 4);
      float xv[16];
      float s1 = 0.f, s2 = 0.f;
#pragma unroll
      for (int t4 = 0; t4 < 4; t4++)
#pragma unroll
        for (int reg = 0; reg < 4; reg++) {
          float v = xr[t4][reg] + acc[t4][p][reg];
          xv[t4 * 4 + reg] = v;
          s1 += v; s2 += v * v;
        }
      s1 += __shfl_xor(s1, 16); s2 += __shfl_xor(s2, 16);
      s1 += __shfl_xor(s1, 32); s2 += __shfl_xor(s2, 32);
      float m = s1 * (1.f / 64.f);
      float var = s2 * (1.f / 64.f) - m * m;
      float sg = rsqrtf(var + 1e-5f);
#pragma unroll
      for (int t4 = 0; t4 < 4; t4++)
#pragma unroll
        for (int reg = 0; reg < 4; reg++) {
          int co = t4 * 16 + quad * 4 + reg;
          xo[((long)b * 64 + co) * NP + px] = xv[t4 * 4 + reg];
        }
      u16* rp = xb2r + ((long)b * NP + px) * 64;
#pragma unroll
      for (int t4 = 0; t4 < 4; t4++) {
        u32 u0 = (u32)f2bf(xv[t4 * 4 + 0] * sg) | ((u32)f2bf(xv[t4 * 4 + 1] * sg) << 16);
        u32 u1 = (u32)f2bf(xv[t4 * 4 + 2] * sg) | ((u32)f2bf(xv[t4 * 4 + 3] * sg) << 16);
        uint2 pk; pk.x = u0; pk.y = u1;
        *(uint2*)(rp + t4 * 16 + quad * 4) = pk;
      }
    }
  }
}

// ---------------- strip-2 dw3x3: 2 output rows (y0,y0+1) x 4 px/lane, packed f32x2 FMA.
__device__ __forceinline__ void dw4x2(const u16* __restrict__ img, int y0, int x0, int lane,
                                      const float* __restrict__ w9,
                                      f32x2 o0[2], f32x2 o1[2]) {
  o0[0] = (f32x2){0.f, 0.f}; o0[1] = (f32x2){0.f, 0.f};
  o1[0] = (f32x2){0.f, 0.f}; o1[1] = (f32x2){0.f, 0.f};
#pragma unroll
  for (int r = -1; r <= 2; r++) {
    int row = y0 + r;
    uint2 q; q.x = 0u; q.y = 0u;
    if ((unsigned)row < 256u) q = *(const uint2*)(img + row * 256 + x0);
    u32 qly = (u32)__shfl_up((int)q.y, 1);
    u32 qrx = (u32)__shfl_down((int)q.x, 1);
    if (lane == 0)  qly = 0u;
    if (lane == 63) qrx = 0u;
    float f[6];
    f[0] = whi(qly); f[1] = wlo(q.x); f[2] = whi(q.x);
    f[3] = wlo(q.y); f[4] = whi(q.y); f[5] = wlo(qrx);
    f32x2 fp[5];
#pragma unroll
    for (int i = 0; i < 5; i++) fp[i] = (f32x2){f[i], f[i + 1]};
    if (r <= 1) {
      const float* wr = w9 + (r + 1) * 3;
#pragma unroll
      for (int dx = 0; dx < 3; dx++) {
        f32x2 w2 = {wr[dx], wr[dx]};
        o0[0] += w2 * fp[dx]; o0[1] += w2 * fp[dx + 2];
      }
    }
    if (r >= 0) {
      const float* wr = w9 + r * 3;
#pragma unroll
      for (int dx = 0; dx < 3; dx++) {
        f32x2 w2 = {wr[dx], wr[dx]};
        o1[0] += w2 * fp[dx]; o1[1] += w2 * fp[dx + 2];
      }
    }
  }
}

// ---------------- q/k/v depthwise + per-pixel norm (q,k only), strip-2.
__global__ __launch_bounds__(256) void k_dwqkv(const u16* __restrict__ P,
                                               const float* __restrict__ dww,
                                               u16* __restrict__ Qn, u16* __restrict__ Kn,
                                               u16* __restrict__ Vn) {
  int t = threadIdx.x;
  int lane = t & 63, wv = t >> 6;
  int by = blockIdx.y;
  int ph = by >> 3, h = by & 7;
  int b = blockIdx.z;
  int y0 = (blockIdx.x * 4 + wv) * 2;
  int x0 = lane * 4;
  int cbase = ph * 64 + h * 8;
  const u16* Pb = P + ((long)b * 192 + cbase) * NP;
  const float* wb = dww + cbase * 9;

  f32x2 v[8][2][2];
#pragma unroll
  for (int c = 0; c < 8; c++)
    dw4x2(Pb + (long)c * NP, y0, x0, lane, wb + c * 9, v[c][0], v[c][1]);

  if (ph < 2) {   // q and k are L2-normalized over the 8 channels per pixel
#pragma unroll
    for (int row = 0; row < 2; row++) {
      f32x2 s2a = {0.f, 0.f}, s2b = {0.f, 0.f};
#pragma unroll
      for (int c = 0; c < 8; c++) {
        s2a += v[c][row][0] * v[c][row][0];
        s2b += v[c][row][1] * v[c][row][1];
      }
      f32x2 ia, ib;
      ia.x = 1.f / (sqrtf(s2a.x) + 1e-6f); ia.y = 1.f / (sqrtf(s2a.y) + 1e-6f);
      ib.x = 1.f / (sqrtf(s2b.x) + 1e-6f); ib.y = 1.f / (sqrtf(s2b.y) + 1e-6f);
#pragma unroll
      for (int c = 0; c < 8; c++) { v[c][row][0] *= ia; v[c][row][1] *= ib; }
    }
  }
  u16* dst = (ph == 0) ? Qn : (ph == 1) ? Kn : Vn;
#pragma unroll
  for (int c = 0; c < 8; c++)
#pragma unroll
    for (int row = 0; row < 2; row++) {
      ushort4 st;
      st.x = f2bf(v[c][row][0].x); st.y = f2bf(v[c][row][0].y);
      st.z = f2bf(v[c][row][1].x); st.w = f2bf(v[c][row][1].y);
      *(ushort4*)(dst + ((long)b * 64 + h * 8 + c) * NP + (long)(y0 + row) * 256 + x0) = st;
    }
}

// ---------------- stats: kv[8][8], ksum[8], vsum[8] per (b,h) from planar Kn/Vn.
__global__ __launch_bounds__(256) void k_stats(const u16* __restrict__ Kn,
                                               const u16* __restrict__ Vn,
                                               float* __restrict__ stats) {
  int t = threadIdx.x;
  int lane = t & 63;
  int h = blockIdx.y, b = blockIdx.z;
  long px = (long)blockIdx.x * 1024 + t * 4;
  const u16* Kb = Kn + ((long)b * 64 + h * 8) * NP + px;
  const u16* Vb = Vn + ((long)b * 64 + h * 8) * NP + px;
  float kf[8][4], vf[8][4];
#pragma unroll
  for (int c = 0; c < 8; c++) {
    ushort4 ku = *(const ushort4*)(Kb + (long)c * NP);
    kf[c][0] = bf2f(ku.x); kf[c][1] = bf2f(ku.y);
    kf[c][2] = bf2f(ku.z); kf[c][3] = bf2f(ku.w);
  }
#pragma unroll
  for (int c = 0; c < 8; c++) {
    ushort4 vu = *(const ushort4*)(Vb + (long)c * NP);
    vf[c][0] = bf2f(vu.x); vf[c][1] = bf2f(vu.y);
    vf[c][2] = bf2f(vu.z); vf[c][3] = bf2f(vu.w);
  }
  __shared__ float sred[80];
  if (t < 80) sred[t] = 0.f;
  __syncthreads();
#pragma unroll
  for (int i = 0; i < 8; i++) {
#pragma unroll
    for (int j = 0; j < 8; j++) {
      float a = kf[i][0] * vf[j][0] + kf[i][1] * vf[j][1] +
                kf[i][2] * vf[j][2] + kf[i][3] * vf[j][3];
      a += __shfl_xor(a, 1); a += __shfl_xor(a, 2); a += __shfl_xor(a, 4);
      a += __shfl_xor(a, 8); a += __shfl_xor(a, 16); a += __shfl_xor(a, 32);
      if (lane == ((i * 8 + j) & 63)) atomicAdd(&sred[i * 8 + j], a);
    }
    {
      float a = kf[i][0] + kf[i][1] + kf[i][2] + kf[i][3];
      a += __shfl_xor(a, 1); a += __shfl_xor(a, 2); a += __shfl_xor(a, 4);
      a += __shfl_xor(a, 8); a += __shfl_xor(a, 16); a += __shfl_xor(a, 32);
      if (lane == ((64 + i) & 63)) atomicAdd(&sred[64 + i], a);
    }
    {
      float a = vf[i][0] + vf[i][1] + vf[i][2] + vf[i][3];
      a += __shfl_xor(a, 1); a += __shfl_xor(a, 2); a += __shfl_xor(a, 4);
      a += __shfl_xor(a, 8); a += __shfl_xor(a, 16); a += __shfl_xor(a, 32);
      if (lane == ((72 + i) & 63)) atomicAdd(&sred[72 + i], a);
    }
  }
  __syncthreads();
  if (t < 80) atomicAdd(&stats[((long)b * 8 + h) * 80 + t], sred[t]);
}

// ---------------- dw1-pairs -> grouped dw2 3x3 -> gelu (strip-2)
__global__ __launch_bounds__(256) void k_dwg(const u16* __restrict__ P,
                                             const float* __restrict__ dw2_w,
                                             u16* __restrict__ G) {
  int t = threadIdx.x;
  int lane = t & 63, wv = t >> 6;
  int c = blockIdx.y, b = blockIdx.z;
  int y0 = (blockIdx.x * 4 + wv) * 2;
  int x0 = lane * 4;
  const u16* Pb = P + (long)b * 128 * NP;
  f32x2 d1r0[2], d1r1[2], d2r0[2], d2r1[2];
  dw4x2(Pb + (long)(2 * c) * NP, y0, x0, lane, dw2_w + c * 18, d1r0, d1r1);
  dw4x2(Pb + (long)(2 * c + 1) * NP, y0, x0, lane, dw2_w + c * 18 + 9, d2r0, d2r1);
  u16* gp = G + ((long)b * 64 + c) * NP + (long)y0 * 256 + x0;
  ushort4 s0, s1;
  s0.x = f2bf(gelu_f(d1r0[0].x + d2r0[0].x)); s0.y = f2bf(gelu_f(d1r0[0].y + d2r0[0].y));
  s0.z = f2bf(gelu_f(d1r0[1].x + d2r0[1].x)); s0.w = f2bf(gelu_f(d1r0[1].y + d2r0[1].y));
  s1.x = f2bf(gelu_f(d1r1[0].x + d2r1[0].x)); s1.y = f2bf(gelu_f(d1r1[0].y + d2r1[0].y));
  s1.z = f2bf(gelu_f(d1r1[1].x + d2r1[1].x)); s1.w = f2bf(gelu_f(d1r1[1].y + d2r1[1].y));
  *(ushort4*)(gp) = s0;
  *(ushort4*)(gp + 256) = s1;
}

// ---------------- FFN dw pair + gelu gate (pair-interleaved P, strip-2)
__global__ __launch_bounds__(256) void k_dwgate(const u16* __restrict__ P,
                                                const float* __restrict__ dww,
                                                u16* __restrict__ Hb) {
  int t = threadIdx.x;
  int lane = t & 63, wv = t >> 6;
  int c = blockIdx.y, b = blockIdx.z;
  int y0 = (blockIdx.x * 4 + wv) * 2;
  int x0 = lane * 4;
  const u16* Pb = P + (long)b * 384 * NP;
  f32x2 d1r0[2], d1r1[2], d2r0[2], d2r1[2];
  dw4x2(Pb + (long)(2 * c) * NP, y0, x0, lane, dww + c * 9, d1r0, d1r1);
  dw4x2(Pb + (long)(2 * c + 1) * NP, y0, x0, lane, dww + (170 + c) * 9, d2r0, d2r1);
  u16* hp = Hb + ((long)b * 170 + c) * NP + (long)y0 * 256 + x0;
  ushort4 s0, s1;
  s0.x = f2bf(gelu_f(d1r0[0].x) * d2r0[0].x); s0.y = f2bf(gelu_f(d1r0[0].y) * d2r0[0].y);
  s0.z = f2bf(gelu_f(d1r0[1].x) * d2r0[1].x); s0.w = f2bf(gelu_f(d1r0[1].y) * d2r0[1].y);
  s1.x = f2bf(gelu_f(d1r1[0].x) * d2r1[0].x); s1.y = f2bf(gelu_f(d1r1[0].y) * d2r1[0].y);
  s1.z = f2bf(gelu_f(d1r1[1].x) * d2r1[1].x); s1.w = f2bf(gelu_f(d1r1[1].y) * d2r1[1].y);
  *(ushort4*)(hp) = s0;
  *(ushort4*)(hp + 256) = s1;
}

// ---------------- refine conv (3/5/7), single-phase strip-2, raw partial sums.
template <int WIN>
__device__ void refine1(const u16* __restrict__ src, const float* __restrict__ wp,
                        float bias, float* __restrict__ ro, int y0, int x0, int lane) {
  const int R = WIN / 2;
  f32x2 a0a = {bias, bias}, a0b = {bias, bias};
  f32x2 a1a = {bias, bias}, a1b = {bias, bias};
#pragma unroll 1
  for (int ch = 0; ch < 8; ch++) {
    const u16* img = src + (long)ch * NP;
    const float* wc = wp + ch * WIN * WIN;
#pragma unroll
    for (int r = -R; r <= 1 + R; r++) {
      int row = y0 + r;
      uint2 q; q.x = 0u; q.y = 0u;
      if ((unsigned)row < 256u) q = *(const uint2*)(img + row * 256 + x0);
      float f[4 + 2 * R];
      f[R + 0] = wlo(q.x); f[R + 1] = whi(q.x);
      f[R + 2] = wlo(q.y); f[R + 3] = whi(q.y);
      {
        u32 qly = (u32)__shfl_up((int)q.y, 1);
        u32 qrx = (u32)__shfl_down((int)q.x, 1);
        if (lane == 0)  qly = 0u;
        if (lane == 63) qrx = 0u;
        f[R - 1] = whi(qly); f[R + 4] = wlo(qrx);
        if (R >= 2) { f[R - 2] = wlo(qly); f[R + 5] = whi(qrx); }
        if (R >= 3) {
          u32 qlx = (u32)__shfl_up((int)q.x, 1);
          u32 qry = (u32)__shfl_down((int)q.y, 1);
          if (lane == 0)  qlx = 0u;
          if (lane == 63) qry = 0u;
          f[0] = whi(qlx); f[R + 6] = wlo(qry);
        }
      }
      f32x2 fp[3 + 2 * R];
#pragma unroll
      for (int i = 0; i < 3 + 2 * R; i++) fp[i] = (f32x2){f[i], f[i + 1]};
      if (r <= R) {
        const float* w0 = wc + (r + R) * WIN;
#pragma unroll
        for (int dx = 0; dx < WIN; dx++) {
          f32x2 w2 = {w0[dx], w0[dx]};
          a0a += w2 * fp[dx];
          a0b += w2 * fp[dx + 2];
        }
      }
      if (r >= 1 - R) {
        const float* w1 = wc + (r - 1 + R) * WIN;
#pragma unroll
        for (int dx = 0; dx < WIN; dx++) {
          f32x2 w2 = {w1[dx], w1[dx]};
          a1a += w2 * fp[dx];
          a1b += w2 * fp[dx + 2];
        }
      }
    }
  }
  float4 o0, o1;
  o0.x = a0a.x; o0.y = a0a.y; o0.z = a0b.x; o0.w = a0b.y;
  o1.x = a1a.x; o1.y = a1a.y; o1.z = a1b.x; o1.w = a1b.y;
  *(float4*)(ro + (long)y0 * 256 + x0) = o0;
  *(float4*)(ro + (long)(y0 + 1) * 256 + x0) = o1;
}

__global__ __launch_bounds__(256) void k_refine(
    const u16* __restrict__ Qn, const u16* __restrict__ Kn,
    const float* __restrict__ r3w, const float* __restrict__ r3b,
    const float* __restrict__ r5w, const float* __restrict__ r5b,
    const float* __restrict__ r7w, const float* __restrict__ r7b,
    float* __restrict__ refQ, float* __restrict__ refK) {
  int t = threadIdx.x, lane = t & 63, wv = t >> 6;
  int yy = blockIdx.y;                  // 16 = (head, phase); heavy WIN=7 heads first
  int h = ((yy >> 1) + 5) & 7;
  int ph = yy & 1;
  int b = blockIdx.z;
  int y0 = (blockIdx.x * 4 + wv) * 2;   // block = 8 contiguous rows (L2 halo reuse)
  int x0 = lane * 4;
  const u16* src = (ph ? Kn : Qn) + ((long)b * 64 + h * 8) * NP;
  float* ro = (ph ? refK : refQ) + ((long)(b * 8 + h)) * NP;
  if (h < 2) {
    float bias = ph ? 0.f : r3b[h];
    refine1<3>(src, r3w + h * 16 * 9 + ph * 8 * 9, bias, ro, y0, x0, lane);
  } else if (h < 5) {
    float bias = ph ? 0.f : r5b[h - 2];
    refine1<5>(src, r5w + (h - 2) * 16 * 25 + ph * 8 * 25, bias, ro, y0, x0, lane);
  } else {
    float bias = ph ? 0.f : r7b[h - 5];
    refine1<7>(src, r7w + (h - 5) * 16 * 49 + ph * 8 * 49, bias, ro, y0, x0, lane);
  }
}

// ---------------- attention epilogue -> O row layout [px][64]; sigmoid(refQ+refK) here
__global__ __launch_bounds__(256) void k_attn(
    const u16* __restrict__ Qn, const float* __restrict__ stats,
    const float* __restrict__ refQ, const float* __restrict__ refK,
    const float* __restrict__ temp,
    const float* __restrict__ xsca, const u16* __restrict__ G,
    u16* __restrict__ Orows) {
  int b = blockIdx.y;
  int t = threadIdx.x;
  __shared__ float s[640];
  __shared__ float sx[64];
  for (int i = t; i < 640; i += 256) s[i] = stats[(long)b * 640 + i];
  if (t < 64) sx[t] = xsca[b * 64 + t];
  __syncthreads();
  long n = (long)blockIdx.x * 256 + t;
  u16* rp = Orows + ((long)b * NP + n) * 64;
#pragma unroll
  for (int h = 0; h < 8; h++) {
    const float* sh = s + h * 80;
    float q[8];
#pragma unroll
    for (int i = 0; i < 8; i++) q[i] = bf2f(Qn[((long)b * 64 + h * 8 + i) * NP + n]);
    float den = 65536.f + 1e-6f;
#pragma unroll
    for (int i = 0; i < 8; i++) den += q[i] * sh[64 + i];
    float rsum = refQ[((long)(b * 8 + h)) * NP + n] + refK[((long)(b * 8 + h)) * NP + n];
    float tr = temp[h] / ((1.f + expf(-rsum)) * den);
    u32 pk[4];
#pragma unroll
    for (int j2 = 0; j2 < 4; j2++) {
      float o01[2];
#pragma unroll
      for (int e = 0; e < 2; e++) {
        int j = j2 * 2 + e;
        float num = sh[72 + j];
#pragma unroll
        for (int i = 0; i < 8; i++) num += q[i] * sh[i * 8 + j];
        int ci = h * 8 + j;
        o01[e] = num * tr * sx[ci] * bf2f(G[((long)b * 64 + ci) * NP + n]);
      }
      pk[j2] = (u32)f2bf(o01[0]) | ((u32)f2bf(o01[1]) << 16);
    }
    uint4 v; v.x = pk[0]; v.y = pk[1]; v.z = pk[2]; v.w = pk[3];
    *(uint4*)(rp + h * 8) = v;
  }
}

// ---------------- pout MFMA GEMM (192-padded -> 64co) + fp32 residual
__global__ __launch_bounds__(256) void k_pout(const u16* __restrict__ Hb,
                                              const u16* __restrict__ Wob,
                                              float* __restrict__ xo) {
  __shared__ u16 tile[64 * 196];   // 25088 B
  int t = threadIdx.x;
  int lane = t & 63, wv = t >> 6;
  int l15 = lane & 15, quad = lane >> 4;
  int b = blockIdx.z;
  int px0 = blockIdx.x * 64;
  const u16* ib = Hb + (long)b * 170 * NP + px0;
#pragma unroll
  for (int i = 0; i < 12; i++) {
    int task = t + i * 256;
    int q = task >> 6, px = task & 63;
    int ci0 = q * 4;
    u32 w0 = 0u, w1 = 0u;
    if (ci0 < 170)     w0 = (u32)ib[(long)ci0 * NP + px];
    if (ci0 + 1 < 170) w0 |= ((u32)ib[(long)(ci0 + 1) * NP + px]) << 16;
    if (ci0 + 2 < 170) w1 = (u32)ib[(long)(ci0 + 2) * NP + px];
    if (ci0 + 3 < 170) w1 |= ((u32)ib[(long)(ci0 + 3) * NP + px]) << 16;
    uint2 pk; pk.x = w0; pk.y = w1;
    *(uint2*)(tile + px * 196 + ci0) = pk;
  }
  __syncthreads();

  f32x4 acc[4];
#pragma unroll
  for (int t4 = 0; t4 < 4; t4++) acc[t4] = (f32x4){0.f, 0.f, 0.f, 0.f};
  const u16* tb = tile + (wv * 16 + l15) * 196;
#pragma unroll
  for (int kf = 0; kf < 6; kf++) {
    union { uint2 u2[2]; short8 s8; } cv;
    cv.u2[0] = *(const uint2*)(tb + kf * 32 + quad * 8);
    cv.u2[1] = *(const uint2*)(tb + kf * 32 + quad * 8 + 4);
    short8 bfr = cv.s8;
#pragma unroll
    for (int t4 = 0; t4 < 4; t4++) {
      short8 aw = *(const short8*)(Wob + (long)(t4 * 16 + l15) * 192 + kf * 32 + quad * 8);
      acc[t4] = __builtin_amdgcn_mfma_f32_16x16x32_bf16(aw, bfr, acc[t4], 0, 0, 0);
    }
  }
  long pxg = px0 + wv * 16 + l15;
  float* xb = xo + (long)b * 64 * NP;
#pragma unroll
  for (int t4 = 0; t4 < 4; t4++)
#pragma unroll
    for (int reg = 0; reg < 4; reg++) {
      int co = t4 * 16 + quad * 4 + reg;
      xb[(long)co * NP + pxg] += acc[t4][reg];
    }
}

// ================================================================ launcher
extern "C" void kernel_launch(void* const* d_in, const int* in_sizes, int n_in,
                              void* d_out, int out_size, void* d_ws, size_t ws_size,
                              hipStream_t stream) {
  const float* x        = (const float*)d_in[0];
  const float* ln1_w    = (const float*)d_in[1];
  const float* sca_w    = (const float*)d_in[2];
  const float* sca_b    = (const float*)d_in[3];
  const float* dw1_w    = (const float*)d_in[4];
  const float* dw2_w    = (const float*)d_in[5];
  const float* qkv_w    = (const float*)d_in[6];
  const float* qkv_dw_w = (const float*)d_in[7];
  const float* temp     = (const float*)d_in[8];
  const float* r3w = (const float*)d_in[9],  *r3b = (const float*)d_in[10];
  const float* r5w = (const float*)d_in[11], *r5b = (const float*)d_in[12];
  const float* r7w = (const float*)d_in[13], *r7b = (const float*)d_in[14];
  const float* proj_w   = (const float*)d_in[15];
  const float* ln2_w    = (const float*)d_in[16];
  const float* pin_w    = (const float*)d_in[17];
  const float* ffn_dw_w = (const float*)d_in[18];
  const float* pout_w   = (const float*)d_in[19];
  float* out = (float*)d_out;
  char* wsb = (char*)d_ws;

  const size_t Mi = 1048576;
  u16* xb1   = (u16*)(wsb);                  // rows [B][NP][64]  (later xb2)
  u16* Qn    = (u16*)(wsb + 32 * Mi);        // planar
  u16* Kn    = (u16*)(wsb + 64 * Mi);        // planar (later O rows)
  u16* G     = (u16*)(wsb + 96 * Mi);        // planar; holds Vn transiently before k_dwg
  u16* Preg  = (u16*)(wsb + 128 * Mi);       // 96 MiB planar
  float* refQ    = (float*)(wsb + 224 * Mi); // 8 MiB (refine q-partial)
  float* refK    = (float*)(wsb + 128 * Mi); // 8 MiB, reuses Preg (free between dwg and FFN)
  float* Fm      = (float*)(wsb + 232 * Mi);
  float* stats   = Fm;
  float* meanraw = Fm + 2560;
  float* xscab   = Fm + 2816;
  u16* Wob       = (u16*)(Fm + 3072);        // 64x192 bf16 pout weights
  u16* W1b = (u16*)(Fm + 13952);
  u16* W2b = W1b + 20480;
  u16* Wpb = W2b + 24576;
  u16* xb2 = xb1;
  u16* Orows = Kn;
  u16* Hb = Qn;
  u16* Vn = G;   // V planes live only between k_dwqkv and k_stats; G written later by k_dwg

  const size_t needed = 232 * Mi + 13952 * 4 + (20480 + 24576 + 4096) * 2;
  if (ws_size < needed) {
    fprintf(stderr, "kernel_launch: ws_size %zu < needed %zu\n", ws_size, needed);
    return;
  }

  hipMemsetAsync(stats, 0, (2560 + 256) * 4, stream);
  k_foldW1b<<<80, 256, 0, stream>>>(qkv_w, dw1_w, ln1_w, W1b);
  k_foldW2b<<<96, 256, 0, stream>>>(pin_w, ln2_w, W2b);
  k_foldWpb<<<16, 256, 0, stream>>>(proj_w, Wpb);
  k_tpoutb<<<48, 256, 0, stream>>>(pout_w, Wob);

  k_ln1<<<dim3(512, BB), 256, 0, stream>>>(x, xb1, meanraw);
  k_xsca<<<1, 256, 0, stream>>>(meanraw, ln1_w, sca_w, sca_b, xscab);

  k_mgemm<0><<<dim3(256, 3, BB), 256, 0, stream>>>(xb1, (long)NP * 64, W1b,
                                                   Preg, 192L * NP, nullptr, nullptr, nullptr);
  k_dwqkv<<<dim3(32, 24, BB), 256, 0, stream>>>(Preg, qkv_dw_w, Qn, Kn, Vn);
  k_stats<<<dim3(64, 8, BB), 256, 0, stream>>>(Kn, Vn, stats);

  k_mgemm<0><<<dim3(256, 2, BB), 256, 0, stream>>>(xb1, (long)NP * 64, W1b + 192 * 64,
                                                   Preg, 128L * NP, nullptr, nullptr, nullptr);
  k_dwg<<<dim3(32, 64, BB), 256, 0, stream>>>(Preg, dw2_w, G);

  k_refine<<<dim3(32, 16, BB), 256, 0, stream>>>(Qn, Kn, r3w, r3b, r5w, r5b, r7w, r7b,
                                                 refQ, refK);
  k_attn<<<dim3(256, BB), 256, 0, stream>>>(Qn, stats, refQ, refK, temp, xscab, G, Orows);

  k_mgemm<1><<<dim3(256, 1, BB), 256, 0, stream>>>(Orows, (long)NP * 64, Wpb,
                                                   nullptr, 0, x, out, xb2);

  for (int pass = 0; pass < 2; pass++) {
    k_mgemm<0><<<dim3(256, 6, 2), 256, 0, stream>>>(xb2 + (long)pass * 2 * NP * 64,
                                                    (long)NP * 64, W2b,
                                                    Preg, 384L * NP, nullptr, nullptr, nullptr);
    k_dwgate<<<dim3(32, 170, 2), 256, 0, stream>>>(Preg, ffn_dw_w,
                                                   Hb + (long)pass * 2 * 170 * NP);
  }
  k_pout<<<dim3(1024, 1, BB), 256, 0, stream>>>(Hb, Wob, out);
}

// Round 7
// 719.078 us; speedup vs baseline: 1.1860x; 1.0059x over previous
//
#include <hip/hip_runtime.h>
#include <math.h>
#include <stdio.h>

#define BB 4
#define NP 65536

typedef unsigned short u16;
typedef unsigned int u32;
typedef __attribute__((ext_vector_type(8))) short short8;
typedef __attribute__((ext_vector_type(4))) float f32x4;
typedef __attribute__((ext_vector_type(2))) float f32x2;

__device__ __forceinline__ float bf2f(u16 u) { return __uint_as_float((u32)u << 16); }
__device__ __forceinline__ u16 f2bf(float f) {
  u32 u = __float_as_uint(f);
  u = (u + 0x7FFFu + ((u >> 16) & 1u)) >> 16;
  return (u16)u;
}
__device__ __forceinline__ float gelu_f(float x) {
  return 0.5f * x * (1.f + erff(x * 0.70710678118654752f));
}
__device__ __forceinline__ float wlo(u32 w) { return __uint_as_float(w << 16); }
__device__ __forceinline__ float whi(u32 w) { return __uint_as_float(w & 0xFFFF0000u); }

// ---------------- LN1 row pass: per-pixel biasfree-LN -> xb1 bf16 rows + SCA mean partials.
// 16 lanes = one pixel (64 ch as 4x float4).  No transpose, no fp32 planar write.
__global__ __launch_bounds__(256) void k_ln1(const float* __restrict__ x,
                                             u16* __restrict__ xb1,
                                             float* __restrict__ meanraw) {
  int t = threadIdx.x;
  int b = blockIdx.y;
  int lane = t & 63;
  int cg = t & 15;
  float a0 = 0.f, a1 = 0.f, a2 = 0.f, a3 = 0.f;
#pragma unroll
  for (int it = 0; it < 8; it++) {
    long px = (long)blockIdx.x * 128 + (t >> 4) + it * 16;
    const float* xr = x + ((long)b * NP + px) * 64 + cg * 4;
    float4 v = *(const float4*)(xr);
    float s1 = v.x + v.y + v.z + v.w;
    float s2 = v.x * v.x + v.y * v.y + v.z * v.z + v.w * v.w;
    s1 += __shfl_xor(s1, 1); s2 += __shfl_xor(s2, 1);
    s1 += __shfl_xor(s1, 2); s2 += __shfl_xor(s2, 2);
    s1 += __shfl_xor(s1, 4); s2 += __shfl_xor(s2, 4);
    s1 += __shfl_xor(s1, 8); s2 += __shfl_xor(s2, 8);
    float m = s1 * (1.f / 64.f);
    float var = s2 * (1.f / 64.f) - m * m;
    float sg = rsqrtf(var + 1e-5f);
    float h0 = v.x * sg, h1 = v.y * sg, h2 = v.z * sg, h3 = v.w * sg;
    uint2 pk;
    pk.x = (u32)f2bf(h0) | ((u32)f2bf(h1) << 16);
    pk.y = (u32)f2bf(h2) | ((u32)f2bf(h3) << 16);
    *(uint2*)(xb1 + ((long)b * NP + px) * 64 + cg * 4) = pk;
    a0 += h0; a1 += h1; a2 += h2; a3 += h3;
  }
  a0 += __shfl_xor(a0, 16); a1 += __shfl_xor(a1, 16);
  a2 += __shfl_xor(a2, 16); a3 += __shfl_xor(a3, 16);
  a0 += __shfl_xor(a0, 32); a1 += __shfl_xor(a1, 32);
  a2 += __shfl_xor(a2, 32); a3 += __shfl_xor(a3, 32);
  __shared__ float cm[64];
  if (t < 64) cm[t] = 0.f;
  __syncthreads();
  if (lane < 16) {
    atomicAdd(&cm[cg * 4 + 0], a0);
    atomicAdd(&cm[cg * 4 + 1], a1);
    atomicAdd(&cm[cg * 4 + 2], a2);
    atomicAdd(&cm[cg * 4 + 3], a3);
  }
  __syncthreads();
  if (t < 64) atomicAdd(&meanraw[b * 64 + t], cm[t]);
}

// ---------------- xsca
__global__ void k_xsca(const float* __restrict__ meanraw, const float* __restrict__ lnw,
                       const float* __restrict__ sca_w, const float* __restrict__ sca_b,
                       float* __restrict__ xsca) {
  int t = threadIdx.x;
  int b = t >> 6, co = t & 63;
  float a = sca_b[co];
  for (int ci = 0; ci < 64; ci++)
    a += sca_w[co * 64 + ci] * meanraw[b * 64 + ci] * lnw[ci] * (1.f / 65536.f);
  xsca[t] = a;
}

// ---------------- weight prep (bf16 [co][64ci], LN folded)
__global__ void k_foldW1b(const float* __restrict__ qkv_w, const float* __restrict__ dw1_w,
                          const float* __restrict__ lnw, u16* __restrict__ W1b) {
  int i = blockIdx.x * 256 + threadIdx.x;
  if (i < 320 * 64) {
    int co = i >> 6, ci = i & 63;
    float w = (co < 192) ? qkv_w[co * 64 + ci] : dw1_w[(co - 192) * 64 + ci];
    W1b[i] = f2bf(w * lnw[ci]);
  }
}
__global__ void k_foldW2b(const float* __restrict__ pin_w, const float* __restrict__ lnw,
                          u16* __restrict__ W2b) {
  int i = blockIdx.x * 256 + threadIdx.x;
  if (i < 384 * 64) {
    int co = i >> 6, ci = i & 63;
    float v = 0.f;
    if (co < 340) {
      int pair = co >> 1, which = co & 1;
      v = pin_w[(pair + which * 170) * 64 + ci] * lnw[ci];
    }
    W2b[i] = f2bf(v);
  }
}
__global__ void k_foldWpb(const float* __restrict__ w, u16* __restrict__ Wpb) {
  int i = blockIdx.x * 256 + threadIdx.x;
  if (i < 4096) Wpb[i] = f2bf(w[i]);
}
// pout weights -> bf16 [64co][192ci], zero-padded ci>=170
__global__ void k_tpoutb(const float* __restrict__ w, u16* __restrict__ Wob) {
  int i = blockIdx.x * 256 + threadIdx.x;
  if (i < 64 * 192) {
    int co = i / 192, ci = i - co * 192;
    Wob[i] = (ci < 170) ? f2bf(w[co * 170 + ci]) : (u16)0;
  }
}

// ---------------- MFMA GEMM: out[co][px] = sum_ci W[co][ci] * in[px][ci]
// EPI==1: residual read from x ROWS (fp32 (B,N,C)), write planar xo + bf16 LN2 rows.
template <int EPI>
__global__ __launch_bounds__(256) void k_mgemm(const u16* __restrict__ in, long in_bs,
                                               const u16* __restrict__ W,
                                               u16* __restrict__ outp, long out_bs,
                                               const float* __restrict__ xres,
                                               float* __restrict__ xo,
                                               u16* __restrict__ xb2r) {
  int t = threadIdx.x;
  int lane = t & 63, wv = t >> 6;
  int l15 = lane & 15, quad = lane >> 4;
  int pxw = blockIdx.x * 256 + wv * 64;
  int co0 = blockIdx.y * 64;
  int b = blockIdx.z;
  const u16* inb = in + (long)b * in_bs;

  short8 aw[4][2];
#pragma unroll
  for (int t4 = 0; t4 < 4; t4++)
#pragma unroll
    for (int kf = 0; kf < 2; kf++)
      aw[t4][kf] = *(const short8*)(W + (long)(co0 + t4 * 16 + l15) * 64 + kf * 32 + quad * 8);

  f32x4 acc[4][4];
#pragma unroll
  for (int t4 = 0; t4 < 4; t4++)
#pragma unroll
    for (int p = 0; p < 4; p++) acc[t4][p] = (f32x4){0.f, 0.f, 0.f, 0.f};

#pragma unroll
  for (int p = 0; p < 4; p++) {
    long px = pxw + p * 16 + l15;
    short8 bf0 = *(const short8*)(inb + px * 64 + quad * 8);
    short8 bf1 = *(const short8*)(inb + px * 64 + 32 + quad * 8);
#pragma unroll
    for (int t4 = 0; t4 < 4; t4++) {
      acc[t4][p] = __builtin_amdgcn_mfma_f32_16x16x32_bf16(aw[t4][0], bf0, acc[t4][p], 0, 0, 0);
      acc[t4][p] = __builtin_amdgcn_mfma_f32_16x16x32_bf16(aw[t4][1], bf1, acc[t4][p], 0, 0, 0);
    }
  }

  if (EPI == 0) {
    u16* ob = outp + (long)b * out_bs;
#pragma unroll
    for (int t4 = 0; t4 < 4; t4++)
#pragma unroll
      for (int p = 0; p < 4; p++) {
#pragma unroll
        for (int reg = 0; reg < 4; reg++) {
          int co = co0 + t4 * 16 + quad * 4 + reg;
          ob[(long)co * NP + pxw + p * 16 + l15] = f2bf(acc[t4][p][reg]);
        }
      }
  } else {
#pragma unroll
    for (int p = 0; p < 4; p++) {
      long px = pxw + p * 16 + l15;
      const float* xrow = xres + ((long)b * NP + px) * 64;
      f32x4 xr[4];
#pragma unroll
      for (int t4 = 0; t4 < 4; t4++)
        xr[t4] = *(const f32x4*)(xrow + t4 * 16 + quad * 4);
      float xv[16];
      float s1 = 0.f, s2 = 0.f;
#pragma unroll
      for (int t4 = 0; t4 < 4; t4++)
#pragma unroll
        for (int reg = 0; reg < 4; reg++) {
          float v = xr[t4][reg] + acc[t4][p][reg];
          xv[t4 * 4 + reg] = v;
          s1 += v; s2 += v * v;
        }
      s1 += __shfl_xor(s1, 16); s2 += __shfl_xor(s2, 16);
      s1 += __shfl_xor(s1, 32); s2 += __shfl_xor(s2, 32);
      float m = s1 * (1.f / 64.f);
      float var = s2 * (1.f / 64.f) - m * m;
      float sg = rsqrtf(var + 1e-5f);
#pragma unroll
      for (int t4 = 0; t4 < 4; t4++)
#pragma unroll
        for (int reg = 0; reg < 4; reg++) {
          int co = t4 * 16 + quad * 4 + reg;
          xo[((long)b * 64 + co) * NP + px] = xv[t4 * 4 + reg];
        }
      u16* rp = xb2r + ((long)b * NP + px) * 64;
#pragma unroll
      for (int t4 = 0; t4 < 4; t4++) {
        u32 u0 = (u32)f2bf(xv[t4 * 4 + 0] * sg) | ((u32)f2bf(xv[t4 * 4 + 1] * sg) << 16);
        u32 u1 = (u32)f2bf(xv[t4 * 4 + 2] * sg) | ((u32)f2bf(xv[t4 * 4 + 3] * sg) << 16);
        uint2 pk; pk.x = u0; pk.y = u1;
        *(uint2*)(rp + t4 * 16 + quad * 4) = pk;
      }
    }
  }
}

// ---------------- strip-2 dw3x3: 2 output rows (y0,y0+1) x 4 px/lane, packed f32x2 FMA.
__device__ __forceinline__ void dw4x2(const u16* __restrict__ img, int y0, int x0, int lane,
                                      const float* __restrict__ w9,
                                      f32x2 o0[2], f32x2 o1[2]) {
  o0[0] = (f32x2){0.f, 0.f}; o0[1] = (f32x2){0.f, 0.f};
  o1[0] = (f32x2){0.f, 0.f}; o1[1] = (f32x2){0.f, 0.f};
#pragma unroll
  for (int r = -1; r <= 2; r++) {
    int row = y0 + r;
    uint2 q; q.x = 0u; q.y = 0u;
    if ((unsigned)row < 256u) q = *(const uint2*)(img + row * 256 + x0);
    u32 qly = (u32)__shfl_up((int)q.y, 1);
    u32 qrx = (u32)__shfl_down((int)q.x, 1);
    if (lane == 0)  qly = 0u;
    if (lane == 63) qrx = 0u;
    float f[6];
    f[0] = whi(qly); f[1] = wlo(q.x); f[2] = whi(q.x);
    f[3] = wlo(q.y); f[4] = whi(q.y); f[5] = wlo(qrx);
    f32x2 fp[5];
#pragma unroll
    for (int i = 0; i < 5; i++) fp[i] = (f32x2){f[i], f[i + 1]};
    if (r <= 1) {
      const float* wr = w9 + (r + 1) * 3;
#pragma unroll
      for (int dx = 0; dx < 3; dx++) {
        f32x2 w2 = {wr[dx], wr[dx]};
        o0[0] += w2 * fp[dx]; o0[1] += w2 * fp[dx + 2];
      }
    }
    if (r >= 0) {
      const float* wr = w9 + r * 3;
#pragma unroll
      for (int dx = 0; dx < 3; dx++) {
        f32x2 w2 = {wr[dx], wr[dx]};
        o1[0] += w2 * fp[dx]; o1[1] += w2 * fp[dx + 2];
      }
    }
  }
}

// ---------------- q/k/v depthwise + per-pixel norm (q,k only), strip-2.
__global__ __launch_bounds__(256) void k_dwqkv(const u16* __restrict__ P,
                                               const float* __restrict__ dww,
                                               u16* __restrict__ Qn, u16* __restrict__ Kn,
                                               u16* __restrict__ Vn) {
  int t = threadIdx.x;
  int lane = t & 63, wv = t >> 6;
  int by = blockIdx.y;
  int ph = by >> 3, h = by & 7;
  int b = blockIdx.z;
  int y0 = (blockIdx.x * 4 + wv) * 2;
  int x0 = lane * 4;
  int cbase = ph * 64 + h * 8;
  const u16* Pb = P + ((long)b * 192 + cbase) * NP;
  const float* wb = dww + cbase * 9;

  f32x2 v[8][2][2];
#pragma unroll
  for (int c = 0; c < 8; c++)
    dw4x2(Pb + (long)c * NP, y0, x0, lane, wb + c * 9, v[c][0], v[c][1]);

  if (ph < 2) {   // q and k are L2-normalized over the 8 channels per pixel
#pragma unroll
    for (int row = 0; row < 2; row++) {
      f32x2 s2a = {0.f, 0.f}, s2b = {0.f, 0.f};
#pragma unroll
      for (int c = 0; c < 8; c++) {
        s2a += v[c][row][0] * v[c][row][0];
        s2b += v[c][row][1] * v[c][row][1];
      }
      f32x2 ia, ib;
      ia.x = 1.f / (sqrtf(s2a.x) + 1e-6f); ia.y = 1.f / (sqrtf(s2a.y) + 1e-6f);
      ib.x = 1.f / (sqrtf(s2b.x) + 1e-6f); ib.y = 1.f / (sqrtf(s2b.y) + 1e-6f);
#pragma unroll
      for (int c = 0; c < 8; c++) { v[c][row][0] *= ia; v[c][row][1] *= ib; }
    }
  }
  u16* dst = (ph == 0) ? Qn : (ph == 1) ? Kn : Vn;
#pragma unroll
  for (int c = 0; c < 8; c++)
#pragma unroll
    for (int row = 0; row < 2; row++) {
      ushort4 st;
      st.x = f2bf(v[c][row][0].x); st.y = f2bf(v[c][row][0].y);
      st.z = f2bf(v[c][row][1].x); st.w = f2bf(v[c][row][1].y);
      *(ushort4*)(dst + ((long)b * 64 + h * 8 + c) * NP + (long)(y0 + row) * 256 + x0) = st;
    }
}

// ---------------- stats: kv[8][8], ksum[8], vsum[8] per (b,h) from planar Kn/Vn.
__global__ __launch_bounds__(256) void k_stats(const u16* __restrict__ Kn,
                                               const u16* __restrict__ Vn,
                                               float* __restrict__ stats) {
  int t = threadIdx.x;
  int lane = t & 63;
  int h = blockIdx.y, b = blockIdx.z;
  long px = (long)blockIdx.x * 1024 + t * 4;
  const u16* Kb = Kn + ((long)b * 64 + h * 8) * NP + px;
  const u16* Vb = Vn + ((long)b * 64 + h * 8) * NP + px;
  float kf[8][4], vf[8][4];
#pragma unroll
  for (int c = 0; c < 8; c++) {
    ushort4 ku = *(const ushort4*)(Kb + (long)c * NP);
    kf[c][0] = bf2f(ku.x); kf[c][1] = bf2f(ku.y);
    kf[c][2] = bf2f(ku.z); kf[c][3] = bf2f(ku.w);
  }
#pragma unroll
  for (int c = 0; c < 8; c++) {
    ushort4 vu = *(const ushort4*)(Vb + (long)c * NP);
    vf[c][0] = bf2f(vu.x); vf[c][1] = bf2f(vu.y);
    vf[c][2] = bf2f(vu.z); vf[c][3] = bf2f(vu.w);
  }
  __shared__ float sred[80];
  if (t < 80) sred[t] = 0.f;
  __syncthreads();
#pragma unroll
  for (int i = 0; i < 8; i++) {
#pragma unroll
    for (int j = 0; j < 8; j++) {
      float a = kf[i][0] * vf[j][0] + kf[i][1] * vf[j][1] +
                kf[i][2] * vf[j][2] + kf[i][3] * vf[j][3];
      a += __shfl_xor(a, 1); a += __shfl_xor(a, 2); a += __shfl_xor(a, 4);
      a += __shfl_xor(a, 8); a += __shfl_xor(a, 16); a += __shfl_xor(a, 32);
      if (lane == ((i * 8 + j) & 63)) atomicAdd(&sred[i * 8 + j], a);
    }
    {
      float a = kf[i][0] + kf[i][1] + kf[i][2] + kf[i][3];
      a += __shfl_xor(a, 1); a += __shfl_xor(a, 2); a += __shfl_xor(a, 4);
      a += __shfl_xor(a, 8); a += __shfl_xor(a, 16); a += __shfl_xor(a, 32);
      if (lane == ((64 + i) & 63)) atomicAdd(&sred[64 + i], a);
    }
    {
      float a = vf[i][0] + vf[i][1] + vf[i][2] + vf[i][3];
      a += __shfl_xor(a, 1); a += __shfl_xor(a, 2); a += __shfl_xor(a, 4);
      a += __shfl_xor(a, 8); a += __shfl_xor(a, 16); a += __shfl_xor(a, 32);
      if (lane == ((72 + i) & 63)) atomicAdd(&sred[72 + i], a);
    }
  }
  __syncthreads();
  if (t < 80) atomicAdd(&stats[((long)b * 8 + h) * 80 + t], sred[t]);
}

// ---------------- dw1-pairs -> grouped dw2 3x3 -> gelu (strip-2)
__global__ __launch_bounds__(256) void k_dwg(const u16* __restrict__ P,
                                             const float* __restrict__ dw2_w,
                                             u16* __restrict__ G) {
  int t = threadIdx.x;
  int lane = t & 63, wv = t >> 6;
  int c = blockIdx.y, b = blockIdx.z;
  int y0 = (blockIdx.x * 4 + wv) * 2;
  int x0 = lane * 4;
  const u16* Pb = P + (long)b * 128 * NP;
  f32x2 d1r0[2], d1r1[2], d2r0[2], d2r1[2];
  dw4x2(Pb + (long)(2 * c) * NP, y0, x0, lane, dw2_w + c * 18, d1r0, d1r1);
  dw4x2(Pb + (long)(2 * c + 1) * NP, y0, x0, lane, dw2_w + c * 18 + 9, d2r0, d2r1);
  u16* gp = G + ((long)b * 64 + c) * NP + (long)y0 * 256 + x0;
  ushort4 s0, s1;
  s0.x = f2bf(gelu_f(d1r0[0].x + d2r0[0].x)); s0.y = f2bf(gelu_f(d1r0[0].y + d2r0[0].y));
  s0.z = f2bf(gelu_f(d1r0[1].x + d2r0[1].x)); s0.w = f2bf(gelu_f(d1r0[1].y + d2r0[1].y));
  s1.x = f2bf(gelu_f(d1r1[0].x + d2r1[0].x)); s1.y = f2bf(gelu_f(d1r1[0].y + d2r1[0].y));
  s1.z = f2bf(gelu_f(d1r1[1].x + d2r1[1].x)); s1.w = f2bf(gelu_f(d1r1[1].y + d2r1[1].y));
  *(ushort4*)(gp) = s0;
  *(ushort4*)(gp + 256) = s1;
}

// ---------------- FFN dw pair + gelu gate (pair-interleaved P, strip-2)
__global__ __launch_bounds__(256) void k_dwgate(const u16* __restrict__ P,
                                                const float* __restrict__ dww,
                                                u16* __restrict__ Hb) {
  int t = threadIdx.x;
  int lane = t & 63, wv = t >> 6;
  int c = blockIdx.y, b = blockIdx.z;
  int y0 = (blockIdx.x * 4 + wv) * 2;
  int x0 = lane * 4;
  const u16* Pb = P + (long)b * 384 * NP;
  f32x2 d1r0[2], d1r1[2], d2r0[2], d2r1[2];
  dw4x2(Pb + (long)(2 * c) * NP, y0, x0, lane, dww + c * 9, d1r0, d1r1);
  dw4x2(Pb + (long)(2 * c + 1) * NP, y0, x0, lane, dww + (170 + c) * 9, d2r0, d2r1);
  u16* hp = Hb + ((long)b * 170 + c) * NP + (long)y0 * 256 + x0;
  ushort4 s0, s1;
  s0.x = f2bf(gelu_f(d1r0[0].x) * d2r0[0].x); s0.y = f2bf(gelu_f(d1r0[0].y) * d2r0[0].y);
  s0.z = f2bf(gelu_f(d1r0[1].x) * d2r0[1].x); s0.w = f2bf(gelu_f(d1r0[1].y) * d2r0[1].y);
  s1.x = f2bf(gelu_f(d1r1[0].x) * d2r1[0].x); s1.y = f2bf(gelu_f(d1r1[0].y) * d2r1[0].y);
  s1.z = f2bf(gelu_f(d1r1[1].x) * d2r1[1].x); s1.w = f2bf(gelu_f(d1r1[1].y) * d2r1[1].y);
  *(ushort4*)(hp) = s0;
  *(ushort4*)(hp + 256) = s1;
}

// ---------------- refine conv (3/5/7), single-phase strip-2, raw partial sums.
template <int WIN>
__device__ void refine1(const u16* __restrict__ src, const float* __restrict__ wp,
                        float bias, float* __restrict__ ro, int y0, int x0, int lane) {
  const int R = WIN / 2;
  f32x2 a0a = {bias, bias}, a0b = {bias, bias};
  f32x2 a1a = {bias, bias}, a1b = {bias, bias};
#pragma unroll 1
  for (int ch = 0; ch < 8; ch++) {
    const u16* img = src + (long)ch * NP;
    const float* wc = wp + ch * WIN * WIN;
#pragma unroll
    for (int r = -R; r <= 1 + R; r++) {
      int row = y0 + r;
      uint2 q; q.x = 0u; q.y = 0u;
      if ((unsigned)row < 256u) q = *(const uint2*)(img + row * 256 + x0);
      float f[4 + 2 * R];
      f[R + 0] = wlo(q.x); f[R + 1] = whi(q.x);
      f[R + 2] = wlo(q.y); f[R + 3] = whi(q.y);
      {
        u32 qly = (u32)__shfl_up((int)q.y, 1);
        u32 qrx = (u32)__shfl_down((int)q.x, 1);
        if (lane == 0)  qly = 0u;
        if (lane == 63) qrx = 0u;
        f[R - 1] = whi(qly); f[R + 4] = wlo(qrx);
        if (R >= 2) { f[R - 2] = wlo(qly); f[R + 5] = whi(qrx); }
        if (R >= 3) {
          u32 qlx = (u32)__shfl_up((int)q.x, 1);
          u32 qry = (u32)__shfl_down((int)q.y, 1);
          if (lane == 0)  qlx = 0u;
          if (lane == 63) qry = 0u;
          f[0] = whi(qlx); f[R + 6] = wlo(qry);
        }
      }
      f32x2 fp[3 + 2 * R];
#pragma unroll
      for (int i = 0; i < 3 + 2 * R; i++) fp[i] = (f32x2){f[i], f[i + 1]};
      if (r <= R) {
        const float* w0 = wc + (r + R) * WIN;
#pragma unroll
        for (int dx = 0; dx < WIN; dx++) {
          f32x2 w2 = {w0[dx], w0[dx]};
          a0a += w2 * fp[dx];
          a0b += w2 * fp[dx + 2];
        }
      }
      if (r >= 1 - R) {
        const float* w1 = wc + (r - 1 + R) * WIN;
#pragma unroll
        for (int dx = 0; dx < WIN; dx++) {
          f32x2 w2 = {w1[dx], w1[dx]};
          a1a += w2 * fp[dx];
          a1b += w2 * fp[dx + 2];
        }
      }
    }
  }
  float4 o0, o1;
  o0.x = a0a.x; o0.y = a0a.y; o0.z = a0b.x; o0.w = a0b.y;
  o1.x = a1a.x; o1.y = a1a.y; o1.z = a1b.x; o1.w = a1b.y;
  *(float4*)(ro + (long)y0 * 256 + x0) = o0;
  *(float4*)(ro + (long)(y0 + 1) * 256 + x0) = o1;
}

__global__ __launch_bounds__(256) void k_refine(
    const u16* __restrict__ Qn, const u16* __restrict__ Kn,
    const float* __restrict__ r3w, const float* __restrict__ r3b,
    const float* __restrict__ r5w, const float* __restrict__ r5b,
    const float* __restrict__ r7w, const float* __restrict__ r7b,
    float* __restrict__ refQ, float* __restrict__ refK) {
  int t = threadIdx.x, lane = t & 63, wv = t >> 6;
  int yy = blockIdx.y;                  // 16 = (head, phase); heavy WIN=7 heads first
  int h = ((yy >> 1) + 5) & 7;
  int ph = yy & 1;
  int b = blockIdx.z;
  int y0 = (blockIdx.x * 4 + wv) * 2;   // block = 8 contiguous rows (L2 halo reuse)
  int x0 = lane * 4;
  const u16* src = (ph ? Kn : Qn) + ((long)b * 64 + h * 8) * NP;
  float* ro = (ph ? refK : refQ) + ((long)(b * 8 + h)) * NP;
  if (h < 2) {
    float bias = ph ? 0.f : r3b[h];
    refine1<3>(src, r3w + h * 16 * 9 + ph * 8 * 9, bias, ro, y0, x0, lane);
  } else if (h < 5) {
    float bias = ph ? 0.f : r5b[h - 2];
    refine1<5>(src, r5w + (h - 2) * 16 * 25 + ph * 8 * 25, bias, ro, y0, x0, lane);
  } else {
    float bias = ph ? 0.f : r7b[h - 5];
    refine1<7>(src, r7w + (h - 5) * 16 * 49 + ph * 8 * 49, bias, ro, y0, x0, lane);
  }
}

// ---------------- attention epilogue -> O row layout [px][64]; sigmoid(refQ+refK) here
__global__ __launch_bounds__(256) void k_attn(
    const u16* __restrict__ Qn, const float* __restrict__ stats,
    const float* __restrict__ refQ, const float* __restrict__ refK,
    const float* __restrict__ temp,
    const float* __restrict__ xsca, const u16* __restrict__ G,
    u16* __restrict__ Orows) {
  int b = blockIdx.y;
  int t = threadIdx.x;
  __shared__ float s[640];
  __shared__ float sx[64];
  for (int i = t; i < 640; i += 256) s[i] = stats[(long)b * 640 + i];
  if (t < 64) sx[t] = xsca[b * 64 + t];
  __syncthreads();
  long n = (long)blockIdx.x * 256 + t;
  u16* rp = Orows + ((long)b * NP + n) * 64;
#pragma unroll
  for (int h = 0; h < 8; h++) {
    const float* sh = s + h * 80;
    float q[8];
#pragma unroll
    for (int i = 0; i < 8; i++) q[i] = bf2f(Qn[((long)b * 64 + h * 8 + i) * NP + n]);
    float den = 65536.f + 1e-6f;
#pragma unroll
    for (int i = 0; i < 8; i++) den += q[i] * sh[64 + i];
    float rsum = refQ[((long)(b * 8 + h)) * NP + n] + refK[((long)(b * 8 + h)) * NP + n];
    float tr = temp[h] / ((1.f + expf(-rsum)) * den);
    u32 pk[4];
#pragma unroll
    for (int j2 = 0; j2 < 4; j2++) {
      float o01[2];
#pragma unroll
      for (int e = 0; e < 2; e++) {
        int j = j2 * 2 + e;
        float num = sh[72 + j];
#pragma unroll
        for (int i = 0; i < 8; i++) num += q[i] * sh[i * 8 + j];
        int ci = h * 8 + j;
        o01[e] = num * tr * sx[ci] * bf2f(G[((long)b * 64 + ci) * NP + n]);
      }
      pk[j2] = (u32)f2bf(o01[0]) | ((u32)f2bf(o01[1]) << 16);
    }
    uint4 v; v.x = pk[0]; v.y = pk[1]; v.z = pk[2]; v.w = pk[3];
    *(uint4*)(rp + h * 8) = v;
  }
}

// ---------------- pout MFMA GEMM (192-padded -> 64co) + fp32 residual.
// Staging: coalesced short8 global loads (wave = 8 ci-rows x 128B), transpose via
// LDS b16 scatter.  Residual prefetched at kernel entry (hides under staging).
__global__ __launch_bounds__(256) void k_pout(const u16* __restrict__ Hb,
                                              const u16* __restrict__ Wob,
                                              float* __restrict__ xo) {
  __shared__ u16 tile[64 * 196];   // [px][ci] pitch 196, 25088 B
  int t = threadIdx.x;
  int lane = t & 63, wv = t >> 6;
  int l15 = lane & 15, quad = lane >> 4;
  int b = blockIdx.z;
  int px0 = blockIdx.x * 64;
  long pxg = px0 + wv * 16 + l15;
  float* xb = xo + (long)b * 64 * NP;

  // prefetch residual (16 independent scalar loads; drain during staging+barrier)
  float res[16];
#pragma unroll
  for (int t4 = 0; t4 < 4; t4++)
#pragma unroll
    for (int reg = 0; reg < 4; reg++) {
      int co = t4 * 16 + quad * 4 + reg;
      res[t4 * 4 + reg] = xb[(long)co * NP + pxg];
    }

  const u16* ib = Hb + (long)b * 170 * NP + px0;
#pragma unroll
  for (int i = 0; i < 6; i++) {
    int task = t + i * 256;          // 1536 = 192 ci x 8 px-octets
    int ci = task >> 3, pxo = task & 7;
    short8 v = {0, 0, 0, 0, 0, 0, 0, 0};
    if (ci < 170) v = *(const short8*)(ib + (long)ci * NP + pxo * 8);
    const u16* vv = (const u16*)&v;
    u16* dst = tile + (pxo * 8) * 196 + ci;
#pragma unroll
    for (int j = 0; j < 8; j++) dst[j * 196] = vv[j];
  }
  __syncthreads();

  f32x4 acc[4];
#pragma unroll
  for (int t4 = 0; t4 < 4; t4++) acc[t4] = (f32x4){0.f, 0.f, 0.f, 0.f};
  const u16* tb = tile + (wv * 16 + l15) * 196;
#pragma unroll
  for (int kf = 0; kf < 6; kf++) {
    union { uint2 u2[2]; short8 s8; } cv;
    cv.u2[0] = *(const uint2*)(tb + kf * 32 + quad * 8);
    cv.u2[1] = *(const uint2*)(tb + kf * 32 + quad * 8 + 4);
    short8 bfr = cv.s8;
#pragma unroll
    for (int t4 = 0; t4 < 4; t4++) {
      short8 aw = *(const short8*)(Wob + (long)(t4 * 16 + l15) * 192 + kf * 32 + quad * 8);
      acc[t4] = __builtin_amdgcn_mfma_f32_16x16x32_bf16(aw, bfr, acc[t4], 0, 0, 0);
    }
  }
#pragma unroll
  for (int t4 = 0; t4 < 4; t4++)
#pragma unroll
    for (int reg = 0; reg < 4; reg++) {
      int co = t4 * 16 + quad * 4 + reg;
      xb[(long)co * NP + pxg] = res[t4 * 4 + reg] + acc[t4][reg];
    }
}

// ================================================================ launcher
extern "C" void kernel_launch(void* const* d_in, const int* in_sizes, int n_in,
                              void* d_out, int out_size, void* d_ws, size_t ws_size,
                              hipStream_t stream) {
  const float* x        = (const float*)d_in[0];
  const float* ln1_w    = (const float*)d_in[1];
  const float* sca_w    = (const float*)d_in[2];
  const float* sca_b    = (const float*)d_in[3];
  const float* dw1_w    = (const float*)d_in[4];
  const float* dw2_w    = (const float*)d_in[5];
  const float* qkv_w    = (const float*)d_in[6];
  const float* qkv_dw_w = (const float*)d_in[7];
  const float* temp     = (const float*)d_in[8];
  const float* r3w = (const float*)d_in[9],  *r3b = (const float*)d_in[10];
  const float* r5w = (const float*)d_in[11], *r5b = (const float*)d_in[12];
  const float* r7w = (const float*)d_in[13], *r7b = (const float*)d_in[14];
  const float* proj_w   = (const float*)d_in[15];
  const float* ln2_w    = (const float*)d_in[16];
  const float* pin_w    = (const float*)d_in[17];
  const float* ffn_dw_w = (const float*)d_in[18];
  const float* pout_w   = (const float*)d_in[19];
  float* out = (float*)d_out;
  char* wsb = (char*)d_ws;

  const size_t Mi = 1048576;
  u16* xb1   = (u16*)(wsb);                  // rows [B][NP][64]  (later xb2)
  u16* Qn    = (u16*)(wsb + 32 * Mi);        // planar
  u16* Kn    = (u16*)(wsb + 64 * Mi);        // planar (later O rows)
  u16* G     = (u16*)(wsb + 96 * Mi);        // planar; holds Vn transiently before k_dwg
  u16* Preg  = (u16*)(wsb + 128 * Mi);       // 96 MiB planar
  float* refQ    = (float*)(wsb + 224 * Mi); // 8 MiB (refine q-partial)
  float* refK    = (float*)(wsb + 128 * Mi); // 8 MiB, reuses Preg (free between dwg and FFN)
  float* Fm      = (float*)(wsb + 232 * Mi);
  float* stats   = Fm;
  float* meanraw = Fm + 2560;
  float* xscab   = Fm + 2816;
  u16* Wob       = (u16*)(Fm + 3072);        // 64x192 bf16 pout weights
  u16* W1b = (u16*)(Fm + 13952);
  u16* W2b = W1b + 20480;
  u16* Wpb = W2b + 24576;
  u16* xb2 = xb1;
  u16* Orows = Kn;
  u16* Hb = Qn;
  u16* Vn = G;   // V planes live only between k_dwqkv and k_stats; G written later by k_dwg

  const size_t needed = 232 * Mi + 13952 * 4 + (20480 + 24576 + 4096) * 2;
  if (ws_size < needed) {
    fprintf(stderr, "kernel_launch: ws_size %zu < needed %zu\n", ws_size, needed);
    return;
  }

  hipMemsetAsync(stats, 0, (2560 + 256) * 4, stream);
  k_foldW1b<<<80, 256, 0, stream>>>(qkv_w, dw1_w, ln1_w, W1b);
  k_foldW2b<<<96, 256, 0, stream>>>(pin_w, ln2_w, W2b);
  k_foldWpb<<<16, 256, 0, stream>>>(proj_w, Wpb);
  k_tpoutb<<<48, 256, 0, stream>>>(pout_w, Wob);

  k_ln1<<<dim3(512, BB), 256, 0, stream>>>(x, xb1, meanraw);
  k_xsca<<<1, 256, 0, stream>>>(meanraw, ln1_w, sca_w, sca_b, xscab);

  k_mgemm<0><<<dim3(256, 3, BB), 256, 0, stream>>>(xb1, (long)NP * 64, W1b,
                                                   Preg, 192L * NP, nullptr, nullptr, nullptr);
  k_dwqkv<<<dim3(32, 24, BB), 256, 0, stream>>>(Preg, qkv_dw_w, Qn, Kn, Vn);
  k_stats<<<dim3(64, 8, BB), 256, 0, stream>>>(Kn, Vn, stats);

  k_mgemm<0><<<dim3(256, 2, BB), 256, 0, stream>>>(xb1, (long)NP * 64, W1b + 192 * 64,
                                                   Preg, 128L * NP, nullptr, nullptr, nullptr);
  k_dwg<<<dim3(32, 64, BB), 256, 0, stream>>>(Preg, dw2_w, G);

  k_refine<<<dim3(32, 16, BB), 256, 0, stream>>>(Qn, Kn, r3w, r3b, r5w, r5b, r7w, r7b,
                                                 refQ, refK);
  k_attn<<<dim3(256, BB), 256, 0, stream>>>(Qn, stats, refQ, refK, temp, xscab, G, Orows);

  k_mgemm<1><<<dim3(256, 1, BB), 256, 0, stream>>>(Orows, (long)NP * 64, Wpb,
                                                   nullptr, 0, x, out, xb2);

  for (int pass = 0; pass < 2; pass++) {
    k_mgemm<0><<<dim3(256, 6, 2), 256, 0, stream>>>(xb2 + (long)pass * 2 * NP * 64,
                                                    (long)NP * 64, W2b,
                                                    Preg, 384L * NP, nullptr, nullptr, nullptr);
    k_dwgate<<<dim3(32, 170, 2), 256, 0, stream>>>(Preg, ffn_dw_w,
                                                   Hb + (long)pass * 2 * 170 * NP);
  }
  k_pout<<<dim3(1024, 1, BB), 256, 0, stream>>>(Hb, Wob, out);
}